// Round 9
// baseline (3724.752 us; speedup 1.0000x reference)
//
#include <hip/hip_runtime.h>

// Problem constants
#define TSEQ 512
#define NB   32     // batch
#define DB   768    // d_bert
#define H2E  128    // encoder hidden per dir
#define DL   256    // d_lstm
#define NC   16     // n_class

typedef unsigned long long ull;
typedef float f32x4 __attribute__((ext_vector_type(4)));

__device__ __forceinline__ float sigf(float x) { return 1.0f / (1.0f + __expf(-x)); }
__device__ __forceinline__ float tanhfast(float x) { return 1.0f - 2.0f / (1.0f + __expf(2.0f * x)); }
__device__ __forceinline__ float rdlane(float v, int lane) {
    return __uint_as_float(__builtin_amdgcn_readlane(__float_as_uint(v), lane));
}

// ---------------------------------------------------------------------------
// f32 GEMM, 64x64 tile (kept for tiny-N q/k projections).
// ---------------------------------------------------------------------------
template <int MODE>
__global__ __launch_bounds__(256) void gemm_nt(
    const float* __restrict__ A, int lda,
    const float* __restrict__ W, int ldw,
    const float* __restrict__ b1, const float* __restrict__ b2,
    float* __restrict__ C, int ldc, int N, int K)
{
    __shared__ float As[16][68];
    __shared__ float Ws[16][68];
    const int tid = threadIdx.x;
    const int m0 = blockIdx.x * 64;
    const int n0 = blockIdx.y * 64;
    const int tx = tid & 15, ty = tid >> 4;
    const int lrow = tid >> 2;
    const int lk = (tid & 3) * 4;
    float acc[4][4] = {};

    for (int k0 = 0; k0 < K; k0 += 16) {
        float4 av = *(const float4*)(A + (size_t)(m0 + lrow) * lda + k0 + lk);
        float4 wv = make_float4(0.f, 0.f, 0.f, 0.f);
        if (n0 + lrow < N)
            wv = *(const float4*)(W + (size_t)(n0 + lrow) * ldw + k0 + lk);
        As[lk + 0][lrow] = av.x; As[lk + 1][lrow] = av.y;
        As[lk + 2][lrow] = av.z; As[lk + 3][lrow] = av.w;
        Ws[lk + 0][lrow] = wv.x; Ws[lk + 1][lrow] = wv.y;
        Ws[lk + 2][lrow] = wv.z; Ws[lk + 3][lrow] = wv.w;
        __syncthreads();
#pragma unroll
        for (int kk = 0; kk < 16; ++kk) {
            float a0 = As[kk][ty * 4 + 0], a1 = As[kk][ty * 4 + 1];
            float a2 = As[kk][ty * 4 + 2], a3 = As[kk][ty * 4 + 3];
            float w0 = Ws[kk][tx * 4 + 0], w1 = Ws[kk][tx * 4 + 1];
            float w2 = Ws[kk][tx * 4 + 2], w3 = Ws[kk][tx * 4 + 3];
            acc[0][0] += a0 * w0; acc[0][1] += a0 * w1; acc[0][2] += a0 * w2; acc[0][3] += a0 * w3;
            acc[1][0] += a1 * w0; acc[1][1] += a1 * w1; acc[1][2] += a1 * w2; acc[1][3] += a1 * w3;
            acc[2][0] += a2 * w0; acc[2][1] += a2 * w1; acc[2][2] += a2 * w2; acc[2][3] += a2 * w3;
            acc[3][0] += a3 * w0; acc[3][1] += a3 * w1; acc[3][2] += a3 * w2; acc[3][3] += a3 * w3;
        }
        __syncthreads();
    }

#pragma unroll
    for (int i = 0; i < 4; ++i) {
        int gm = m0 + ty * 4 + i;
        int orow;
        if (MODE == 0) orow = gm;
        else {
            int bb = gm >> 9;
            int tt = gm & (TSEQ - 1);
            orow = (MODE == 1 ? tt : (TSEQ - 1 - tt)) * NB + bb;
        }
#pragma unroll
        for (int j = 0; j < 4; ++j) {
            int gn = n0 + tx * 4 + j;
            if (gn < N) {
                float bias = (b1 ? b1[gn] : 0.f) + (b2 ? b2[gn] : 0.f);
                C[(size_t)orow * ldc + gn] = acc[i][j] + bias;
            }
        }
    }
}

// ---------------------------------------------------------------------------
// f32 GEMM, 128x64 tile, 8x4 microtile.
// ---------------------------------------------------------------------------
template <int MODE>
__global__ __launch_bounds__(256) void gemm_nt128(
    const float* __restrict__ A, int lda,
    const float* __restrict__ W, int ldw,
    const float* __restrict__ b1, const float* __restrict__ b2,
    float* __restrict__ C, int ldc, int N, int K)
{
    __shared__ float As[16][132];
    __shared__ float Ws[16][68];
    const int tid = threadIdx.x;
    const int m0 = blockIdx.x * 128;
    const int n0 = blockIdx.y * 64;
    const int tx = tid & 15, ty = tid >> 4;
    const int lrow = tid >> 1, lk = (tid & 1) * 8;
    const int wrow = tid >> 2, wk = (tid & 3) * 4;
    float acc[8][4] = {};

    for (int k0 = 0; k0 < K; k0 += 16) {
        float4 a0v = *(const float4*)(A + (size_t)(m0 + lrow) * lda + k0 + lk);
        float4 a1v = *(const float4*)(A + (size_t)(m0 + lrow) * lda + k0 + lk + 4);
        float4 wv = make_float4(0.f, 0.f, 0.f, 0.f);
        if (n0 + wrow < N)
            wv = *(const float4*)(W + (size_t)(n0 + wrow) * ldw + k0 + wk);
        As[lk + 0][lrow] = a0v.x; As[lk + 1][lrow] = a0v.y;
        As[lk + 2][lrow] = a0v.z; As[lk + 3][lrow] = a0v.w;
        As[lk + 4][lrow] = a1v.x; As[lk + 5][lrow] = a1v.y;
        As[lk + 6][lrow] = a1v.z; As[lk + 7][lrow] = a1v.w;
        Ws[wk + 0][wrow] = wv.x; Ws[wk + 1][wrow] = wv.y;
        Ws[wk + 2][wrow] = wv.z; Ws[wk + 3][wrow] = wv.w;
        __syncthreads();
#pragma unroll
        for (int kk = 0; kk < 16; ++kk) {
            float a[8], w[4];
#pragma unroll
            for (int i = 0; i < 8; ++i) a[i] = As[kk][ty * 8 + i];
#pragma unroll
            for (int j = 0; j < 4; ++j) w[j] = Ws[kk][tx * 4 + j];
#pragma unroll
            for (int i = 0; i < 8; ++i)
#pragma unroll
                for (int j = 0; j < 4; ++j)
                    acc[i][j] += a[i] * w[j];
        }
        __syncthreads();
    }

#pragma unroll
    for (int i = 0; i < 8; ++i) {
        int gm = m0 + ty * 8 + i;
        int orow;
        if (MODE == 0) orow = gm;
        else {
            int bb = gm >> 9;
            int tt = gm & (TSEQ - 1);
            orow = (MODE == 1 ? tt : (TSEQ - 1 - tt)) * NB + bb;
        }
#pragma unroll
        for (int j = 0; j < 4; ++j) {
            int gn = n0 + tx * 4 + j;
            if (gn < N) {
                float bias = (b1 ? b1[gn] : 0.f) + (b2 ? b2[gn] : 0.f);
                C[(size_t)orow * ldc + gn] = acc[i][j] + bias;
            }
        }
    }
}

// ---------------------------------------------------------------------------
// Encoder LSTM scan (unchanged).
// ---------------------------------------------------------------------------
__global__ __launch_bounds__(512) void enc_scan(
    const float* __restrict__ Gf, const float* __restrict__ Gr,
    const float* __restrict__ Whh_f, const float* __restrict__ Whh_r,
    float* __restrict__ hs_ctx)
{
    const int dir = blockIdx.x & 1;
    const int b = blockIdx.x >> 1;
    const float* __restrict__ G = dir ? Gr : Gf;
    const float* __restrict__ Whh = dir ? Whh_r : Whh_f;
    const int j = threadIdx.x;

    __shared__ float4 h4[H2E / 4];
    __shared__ float gates[4 * H2E];
    float* h_s = (float*)h4;

    float4 w[32];
#pragma unroll
    for (int k = 0; k < 32; ++k)
        w[k] = *(const float4*)(Whh + (size_t)j * H2E + k * 4);

    float c = 0.f;
    if (j < H2E) h_s[j] = 0.f;
    __syncthreads();

    for (int t = 0; t < TSEQ; ++t) {
        const float* grow = G + ((size_t)t * NB + b) * 512;
        float acc = grow[j];
#pragma unroll
        for (int k = 0; k < 32; ++k) {
            float4 hv = h4[k];
            acc += w[k].x * hv.x + w[k].y * hv.y + w[k].z * hv.z + w[k].w * hv.w;
        }
        gates[j] = acc;
        __syncthreads();
        if (j < H2E) {
            float ig = sigf(gates[j]);
            float fg = sigf(gates[j + H2E]);
            float gg = tanhfast(gates[j + 2 * H2E]);
            float og = sigf(gates[j + 3 * H2E]);
            c = fg * c + ig * gg;
            float h = og * tanhfast(c);
            h_s[j] = h;
            int tout = dir ? (TSEQ - 1 - t) : t;
            hs_ctx[((size_t)b * TSEQ + tout) * 512 + dir * H2E + j] = h;
        }
        __syncthreads();
    }
}

// ---------------------------------------------------------------------------
// Fused additive-attention scores + softmax (unchanged).
// ---------------------------------------------------------------------------
__global__ __launch_bounds__(256) void attn_w(
    const float* __restrict__ qp, const float* __restrict__ kp,
    const int* __restrict__ mask, const float* __restrict__ fc2,
    float* __restrict__ wout)
{
    const int bi = blockIdx.x;
    const int b = bi >> 9;
    const int tid = threadIdx.x;
    __shared__ float kps[TSEQ * 11];
    __shared__ float red[8];

    const float* kpb = kp + (size_t)b * TSEQ * 10;
    for (int idx = tid; idx < TSEQ * 10; idx += 256) {
        int j = idx / 10, xx = idx - j * 10;
        kps[j * 11 + xx] = kpb[idx];
    }
    float q[10], vv[10];
#pragma unroll
    for (int xx = 0; xx < 10; ++xx) {
        q[xx] = qp[(size_t)bi * 10 + xx];
        vv[xx] = fc2[xx];
    }
    __syncthreads();

    float a[2];
#pragma unroll
    for (int jj = 0; jj < 2; ++jj) {
        int j = tid + jj * 256;
        float s = 0.f;
#pragma unroll
        for (int xx = 0; xx < 10; ++xx)
            s += vv[xx] * tanhfast(q[xx] + kps[j * 11 + xx]);
        if (mask[(size_t)b * TSEQ + j] == 0) s = -1e30f;
        a[jj] = s;
    }

    float m = fmaxf(a[0], a[1]);
#pragma unroll
    for (int o = 32; o >= 1; o >>= 1) m = fmaxf(m, __shfl_xor(m, o));
    if ((tid & 63) == 0) red[tid >> 6] = m;
    __syncthreads();
    m = fmaxf(fmaxf(red[0], red[1]), fmaxf(red[2], red[3]));

    float e0 = __expf(a[0] - m), e1 = __expf(a[1] - m);
    float s = e0 + e1;
#pragma unroll
    for (int o = 32; o >= 1; o >>= 1) s += __shfl_xor(s, o);
    if ((tid & 63) == 0) red[4 + (tid >> 6)] = s;
    __syncthreads();
    s = (red[4] + red[5]) + (red[6] + red[7]);
    float inv = 1.0f / s;
    wout[(size_t)bi * TSEQ + tid] = e0 * inv;
    wout[(size_t)bi * TSEQ + tid + 256] = e1 * inv;
}

// ---------------------------------------------------------------------------
// Batched NN GEMM: ctx = w @ hs (unchanged).
// ---------------------------------------------------------------------------
__global__ __launch_bounds__(256) void bgemm_nn(
    const float* __restrict__ Wmat,
    float* __restrict__ hs_ctx)
{
    __shared__ float As[16][68];
    __shared__ float Bs[16][68];
    const int tid = threadIdx.x;
    const int b = blockIdx.z;
    const int i0 = blockIdx.x * 64;
    const int d0 = blockIdx.y * 64;
    const int tx = tid & 15, ty = tid >> 4;
    float acc[4][4] = {};
    const float* Ab = Wmat + (size_t)b * TSEQ * TSEQ;
    const float* Bb = hs_ctx + (size_t)b * TSEQ * 512;

    for (int k0 = 0; k0 < TSEQ; k0 += 16) {
        {
            int r = tid >> 2, kq = (tid & 3) * 4;
            float4 v = *(const float4*)(Ab + (size_t)(i0 + r) * TSEQ + k0 + kq);
            As[kq + 0][r] = v.x; As[kq + 1][r] = v.y; As[kq + 2][r] = v.z; As[kq + 3][r] = v.w;
        }
        {
            int kk = tid >> 4, dq = (tid & 15) * 4;
            float4 v = *(const float4*)(Bb + (size_t)(k0 + kk) * 512 + d0 + dq);
            *(float4*)&Bs[kk][dq] = v;
        }
        __syncthreads();
#pragma unroll
        for (int kk = 0; kk < 16; ++kk) {
            float a0 = As[kk][ty * 4 + 0], a1 = As[kk][ty * 4 + 1];
            float a2 = As[kk][ty * 4 + 2], a3 = As[kk][ty * 4 + 3];
            float b0 = Bs[kk][tx * 4 + 0], b1 = Bs[kk][tx * 4 + 1];
            float b2 = Bs[kk][tx * 4 + 2], b3 = Bs[kk][tx * 4 + 3];
            acc[0][0] += a0 * b0; acc[0][1] += a0 * b1; acc[0][2] += a0 * b2; acc[0][3] += a0 * b3;
            acc[1][0] += a1 * b0; acc[1][1] += a1 * b1; acc[1][2] += a1 * b2; acc[1][3] += a1 * b3;
            acc[2][0] += a2 * b0; acc[2][1] += a2 * b1; acc[2][2] += a2 * b2; acc[2][3] += a2 * b3;
            acc[3][0] += a3 * b0; acc[3][1] += a3 * b1; acc[3][2] += a3 * b2; acc[3][3] += a3 * b3;
        }
        __syncthreads();
    }
#pragma unroll
    for (int i = 0; i < 4; ++i)
#pragma unroll
        for (int j = 0; j < 4; ++j)
            hs_ctx[((size_t)b * TSEQ + i0 + ty * 4 + i) * 512 + 256 + d0 + tx * 4 + j] = acc[i][j];
}

// ---------------------------------------------------------------------------
// Decoder init (unchanged): clear all tags, seed h(-1) tag=1 parity 0.
// ---------------------------------------------------------------------------
__global__ __launch_bounds__(256) void dec_init4(
    const float* __restrict__ hs_ctx, ull* hbuf, ull* lbuf)
{
    const int gid = blockIdx.x * 256 + threadIdx.x;
    for (int idx = gid; idx < 32768; idx += 16 * 256) {
        ull v = 0ull;
        if (idx < 8192) {
            int b = idx >> 8, u = idx & 255;
            float hv = hs_ctx[((size_t)b * TSEQ + (TSEQ - 1)) * 512 + u];
            v = (1ull << 32) | (ull)__float_as_uint(hv);
        }
        ull* dst = (idx < 16384) ? (hbuf + idx) : (lbuf + (idx - 16384));
        __hip_atomic_store(dst, v, __ATOMIC_RELAXED, __HIP_MEMORY_SCOPE_AGENT);
    }
}

// ---------------------------------------------------------------------------
// Decoder scan v8: register-file h-broadcast via v_readlane.
// After the tag-verify, wave kseg's lane l holds h(t-1)[bb][kseg*64+l] for
// bb=0..3 in VGPRs -- exactly its kseg window. The gate dot broadcasts h with
// readlane (VALU) instead of ds_read_b128: LDS traffic drops to the w-row
// b128 reads, stored group-XOR-swizzled (g^=row&7 on 16B groups, stride 256)
// so each bank is hit exactly 8x (minimum). No hlds staging at all.
// Tag sync / wave1 y-path / finalize identical to the validated v6 scheme.
// ---------------------------------------------------------------------------
__global__ __launch_bounds__(256) void dec_scan7(
    const float* __restrict__ Gd,     // (T, NB, 1024), biases folded
    const float* __restrict__ Whh,    // (1024, 256)
    const float* __restrict__ Wih,    // (1024, 272); cols 256:272 multiply y
    const float* __restrict__ lin_w,  // (16, 256)
    const float* __restrict__ lin_b,  // (16,)
    ull* hbuf,                        // (2, NB, 256) tagged h
    ull* lbuf,                        // (2, NB, 256) tagged logit partials
    float* __restrict__ out)          // (NB, T, NC)
{
    const int tid = threadIdx.x;
    const int rg  = blockIdx.x & 15;
    const int bg  = blockIdx.x >> 4;
    const int kseg = tid >> 6;        // wave id 0..3
    const int rr   = tid & 63;        // gate row 0..63 within block
    const bool isw1 = (kseg == 1);
    const int ybb = (tid >> 4) & 3;
    const int ycls = tid & 15;
    const int swz = rr & 7;

    __shared__ float wlds[64][256];   // Whh slice, group-XOR-swizzled
    __shared__ float part[4][4][66];  // [bb][kseg][rr] gate partials
    __shared__ float ylds[4][17];     // y(t-1)
    __shared__ float hnew[4][17];     // new h slice (wave0-internal)
    __shared__ float linl[16][17];    // lin_w[cls][rg*16+u]
    __shared__ float wylds[64][17];   // y-weights for our 64 rows

    // ---- one-time staging ----
    for (int idx = tid; idx < 64 * 256; idx += 256) {
        int row = idx >> 8, c = idx & 255;
        int j = ((row >> 4) << 8) + rg * 16 + (row & 15);
        int cs = (((c >> 2) ^ (row & 7)) << 2) | (c & 3);
        wlds[row][cs] = Whh[(size_t)j * 256 + c];
    }
    {
        int r = tid >> 2, c0 = (tid & 3) * 4;
        int j = ((r >> 4) << 8) + rg * 16 + (r & 15);
        const float* src = Wih + (size_t)j * 272 + 256 + c0;
        wylds[r][c0 + 0] = src[0]; wylds[r][c0 + 1] = src[1];
        wylds[r][c0 + 2] = src[2]; wylds[r][c0 + 3] = src[3];
    }
    linl[tid >> 4][tid & 15] = lin_w[(tid >> 4) * 256 + rg * 16 + (tid & 15)];
    const float lb = lin_b[ycls];
    const int jrow = ((rr >> 4) << 8) + rg * 16 + (rr & 15);
    float cstate = 0.f;
    __syncthreads();

    for (int t = 0; t <= TSEQ; ++t) {
        const unsigned want = (unsigned)(t + 1);
        const ull* hsrc = hbuf + (size_t)(t & 1) * 8192 + (size_t)bg * 1024;
        const ull* lsrc = lbuf + (size_t)(t & 1) * 8192 + (size_t)bg * 1024;

        // Gd prefetch (h-independent), wave0 only
        float gv0 = 0.f, gv1 = 0.f, gv2 = 0.f, gv3 = 0.f;
        if (kseg == 0 && t < TSEQ) {
            const float* gb = Gd + ((size_t)t * NB + bg * 4) * 1024 + jrow;
            gv0 = gb[0]; gv1 = gb[1024]; gv2 = gb[2048]; gv3 = gb[3072];
        }
        __builtin_amdgcn_sched_barrier(0);

        // ---- wave1: y-path (poll tagged logit partials, softmax, out) ----
        if (isw1) {
            float yv = 0.f;
            if (t > 0) {
                float lsum;
                for (;;) {
                    lsum = lb;
                    bool ok = true;
#pragma unroll
                    for (int r = 0; r < 16; ++r) {
                        ull lv = __hip_atomic_load(lsrc + ybb * 256 + r * 16 + ycls,
                                                   __ATOMIC_RELAXED, __HIP_MEMORY_SCOPE_AGENT);
                        ok &= ((unsigned)(lv >> 32) == want);
                        lsum += __uint_as_float((unsigned)lv);
                    }
                    if (ok) break;
                    __builtin_amdgcn_s_sleep(1);
                }
                float m = lsum;
#pragma unroll
                for (int o = 1; o < 16; o <<= 1) m = fmaxf(m, __shfl_xor(m, o, 16));
                float e = __expf(lsum - m);
                float ss = e;
#pragma unroll
                for (int o = 1; o < 16; o <<= 1) ss += __shfl_xor(ss, o, 16);
                yv = e / ss;
                if (rg == 0)
                    out[(((size_t)(bg * 4 + ybb)) * TSEQ + (t - 1)) * NC + ycls] = yv;
            }
            ylds[ybb][ycls] = yv;
        }

        // ---- all threads: verify own 4 tagged h-words; keep h in VGPRs ----
        float hr0, hr1, hr2, hr3;
        {
            ull h0, h1, h2, h3;
            for (;;) {
                h0 = __hip_atomic_load(hsrc + tid,       __ATOMIC_RELAXED, __HIP_MEMORY_SCOPE_AGENT);
                h1 = __hip_atomic_load(hsrc + tid + 256, __ATOMIC_RELAXED, __HIP_MEMORY_SCOPE_AGENT);
                h2 = __hip_atomic_load(hsrc + tid + 512, __ATOMIC_RELAXED, __HIP_MEMORY_SCOPE_AGENT);
                h3 = __hip_atomic_load(hsrc + tid + 768, __ATOMIC_RELAXED, __HIP_MEMORY_SCOPE_AGENT);
                if (((unsigned)(h0 >> 32) == want) && ((unsigned)(h1 >> 32) == want) &&
                    ((unsigned)(h2 >> 32) == want) && ((unsigned)(h3 >> 32) == want))
                    break;
                __builtin_amdgcn_s_sleep(1);
            }
            hr0 = __uint_as_float((unsigned)h0);
            hr1 = __uint_as_float((unsigned)h1);
            hr2 = __uint_as_float((unsigned)h2);
            hr3 = __uint_as_float((unsigned)h3);
        }
        __syncthreads();   // ylds ready; part WAR from previous finalize cleared

        if (t == TSEQ) break;

        // ---- gate partials: LDS w (swizzled b128) x readlane h broadcast ----
        {
            float a0 = gv0, a1 = gv1, a2 = gv2, a3 = gv3;
#pragma unroll
            for (int i = 0; i < 16; ++i) {
                const int g = ((kseg << 4) + i) ^ swz;
                f32x4 w4 = *(const f32x4*)&wlds[rr][g << 2];
#pragma unroll
                for (int e = 0; e < 4; ++e) {
                    const int lane = i * 4 + e;
                    const float w = w4[e];
                    a0 += w * rdlane(hr0, lane);
                    a1 += w * rdlane(hr1, lane);
                    a2 += w * rdlane(hr2, lane);
                    a3 += w * rdlane(hr3, lane);
                }
            }
            part[0][kseg][rr] = a0;
            part[1][kseg][rr] = a1;
            part[2][kseg][rr] = a2;
            part[3][kseg][rr] = a3;
        }
        __syncthreads();   // part ready

        // ---- finalize (wave0): ksegs + y-term, nonlinearity, publish ----
        if (tid < 64) {
            const int bb = ybb, u = ycls;
            float g[4];
#pragma unroll
            for (int q = 0; q < 4; ++q) {
                const int r = q * 16 + u;
                float s = part[bb][0][r] + part[bb][1][r]
                        + part[bb][2][r] + part[bb][3][r];
#pragma unroll
                for (int c = 0; c < 16; ++c)
                    s += wylds[r][c] * ylds[bb][c];
                g[q] = s;
            }
            float ig = sigf(g[0]), fg = sigf(g[1]);
            float gv = tanhfast(g[2]), og = sigf(g[3]);
            cstate = fg * cstate + ig * gv;
            float h = og * tanhfast(cstate);
            hnew[bb][u] = h;
            const ull tagbits = ((ull)(unsigned)(t + 2)) << 32;
            const size_t oidx = (size_t)((t + 1) & 1) * 8192
                              + (size_t)(bg * 4 + bb) * 256 + rg * 16 + u;
            __hip_atomic_store(hbuf + oidx, tagbits | (ull)__float_as_uint(h),
                               __ATOMIC_RELAXED, __HIP_MEMORY_SCOPE_AGENT);
            float lp = 0.f;
#pragma unroll
            for (int u2 = 0; u2 < 16; ++u2)
                lp += linl[u][u2] * hnew[bb][u2];
            __hip_atomic_store(lbuf + oidx, tagbits | (ull)__float_as_uint(lp),
                               __ATOMIC_RELAXED, __HIP_MEMORY_SCOPE_AGENT);
        }
        // no trailing barrier: next-step verify self-gates on our publish
    }
}

// ---------------------------------------------------------------------------
extern "C" void kernel_launch(void* const* d_in, const int* in_sizes, int n_in,
                              void* d_out, int out_size, void* d_ws, size_t ws_size,
                              hipStream_t stream)
{
    const float* x     = (const float*)d_in[0];
    const int*   mask  = (const int*)d_in[1];
    const float* Wih_f = (const float*)d_in[2];
    const float* Whh_f = (const float*)d_in[3];
    const float* bih_f = (const float*)d_in[4];
    const float* bhh_f = (const float*)d_in[5];
    const float* Wih_r = (const float*)d_in[6];
    const float* Whh_r = (const float*)d_in[7];
    const float* bih_r = (const float*)d_in[8];
    const float* bhh_r = (const float*)d_in[9];
    const float* fc1_w = (const float*)d_in[10];
    const float* fc2_w = (const float*)d_in[11];
    const float* fc3_w = (const float*)d_in[12];
    const float* fc3_b = (const float*)d_in[13];
    const float* Wih_d = (const float*)d_in[14];
    const float* Whh_d = (const float*)d_in[15];
    const float* bih_d = (const float*)d_in[16];
    const float* bhh_d = (const float*)d_in[17];
    const float* lin_w = (const float*)d_in[18];
    const float* lin_b = (const float*)d_in[19];

    float* ws = (float*)d_ws;
    float* Gf   = ws;
    float* Gr   = ws + 8388608;
    float* hs   = ws + 16777216;
    float* wat  = ws + 25165824;
    float* qp   = ws + 33554432;
    float* kp   = ws + 33718272;
    float* Gd   = ws;
    float* yenc = wat;
    ull* hbuf = (ull*)(wat + 4194304);
    ull* lbuf = hbuf + 16384;

    float* outp = (float*)d_out;
    const int M = NB * TSEQ;       // 16384
    dim3 blk(256);

    // 1-2. encoder input projections (128x64 tiles)
    gemm_nt128<1><<<dim3(M / 128, 8), blk, 0, stream>>>(x, DB, Wih_f, DB, bih_f, bhh_f, Gf, 512, 512, DB);
    gemm_nt128<2><<<dim3(M / 128, 8), blk, 0, stream>>>(x, DB, Wih_r, DB, bih_r, bhh_r, Gr, 512, 512, DB);
    // 3. bidirectional recurrence
    enc_scan<<<dim3(64), dim3(512), 0, stream>>>(Gf, Gr, Whh_f, Whh_r, hs);
    // 4-5. q/k projections (tiny N, 64x64)
    gemm_nt<0><<<dim3(M / 64, 1), blk, 0, stream>>>(hs, 512, fc1_w, 512, nullptr, nullptr, qp, 10, 10, 256);
    gemm_nt<0><<<dim3(M / 64, 1), blk, 0, stream>>>(hs, 512, fc1_w + 256, 512, nullptr, nullptr, kp, 10, 10, 256);
    // 6. attention scores + softmax
    attn_w<<<dim3(M), blk, 0, stream>>>(qp, kp, mask, fc2_w, wat);
    // 7. ctx = w @ hs
    bgemm_nn<<<dim3(8, 4, NB), blk, 0, stream>>>(wat, hs);
    // 8. y_enc (128x64)
    gemm_nt128<0><<<dim3(M / 128, 4), blk, 0, stream>>>(hs, 512, fc3_w, 512, fc3_b, nullptr, yenc, 256, 256, 512);
    // 8.5 decoder comm init
    dec_init4<<<dim3(16), blk, 0, stream>>>(hs, hbuf, lbuf);
    // 9. decoder input projection (128x64)
    gemm_nt128<1><<<dim3(M / 128, 16), blk, 0, stream>>>(yenc, 256, Wih_d, 272, bih_d, bhh_d, Gd, 1024, 1024, 256);
    // 10. decoder recurrence (readlane h-broadcast + swizzled LDS weights)
    dec_scan7<<<dim3(128), blk, 0, stream>>>(Gd, Whh_d, Wih_d, lin_w, lin_b, hbuf, lbuf, outp);
}

// Round 10
// 3412.800 us; speedup vs baseline: 1.0914x; 1.0914x over previous
//
#include <hip/hip_runtime.h>

// Problem constants
#define TSEQ 512
#define NB   32     // batch
#define DB   768    // d_bert
#define H2E  128    // encoder hidden per dir
#define DL   256    // d_lstm
#define NC   16     // n_class

typedef unsigned long long ull;
typedef float f32x4 __attribute__((ext_vector_type(4)));

__device__ __forceinline__ float sigf(float x) { return 1.0f / (1.0f + __expf(-x)); }
__device__ __forceinline__ float tanhfast(float x) { return 1.0f - 2.0f / (1.0f + __expf(2.0f * x)); }

// ---------------------------------------------------------------------------
// f32 GEMM, 64x64 tile (tiny-N q/k projections only).
// ---------------------------------------------------------------------------
template <int MODE>
__global__ __launch_bounds__(256) void gemm_nt(
    const float* __restrict__ A, int lda,
    const float* __restrict__ W, int ldw,
    const float* __restrict__ b1, const float* __restrict__ b2,
    float* __restrict__ C, int ldc, int N, int K)
{
    __shared__ float As[16][68];
    __shared__ float Ws[16][68];
    const int tid = threadIdx.x;
    const int m0 = blockIdx.x * 64;
    const int n0 = blockIdx.y * 64;
    const int tx = tid & 15, ty = tid >> 4;
    const int lrow = tid >> 2;
    const int lk = (tid & 3) * 4;
    float acc[4][4] = {};

    for (int k0 = 0; k0 < K; k0 += 16) {
        float4 av = *(const float4*)(A + (size_t)(m0 + lrow) * lda + k0 + lk);
        float4 wv = make_float4(0.f, 0.f, 0.f, 0.f);
        if (n0 + lrow < N)
            wv = *(const float4*)(W + (size_t)(n0 + lrow) * ldw + k0 + lk);
        As[lk + 0][lrow] = av.x; As[lk + 1][lrow] = av.y;
        As[lk + 2][lrow] = av.z; As[lk + 3][lrow] = av.w;
        Ws[lk + 0][lrow] = wv.x; Ws[lk + 1][lrow] = wv.y;
        Ws[lk + 2][lrow] = wv.z; Ws[lk + 3][lrow] = wv.w;
        __syncthreads();
#pragma unroll
        for (int kk = 0; kk < 16; ++kk) {
            float a0 = As[kk][ty * 4 + 0], a1 = As[kk][ty * 4 + 1];
            float a2 = As[kk][ty * 4 + 2], a3 = As[kk][ty * 4 + 3];
            float w0 = Ws[kk][tx * 4 + 0], w1 = Ws[kk][tx * 4 + 1];
            float w2 = Ws[kk][tx * 4 + 2], w3 = Ws[kk][tx * 4 + 3];
            acc[0][0] += a0 * w0; acc[0][1] += a0 * w1; acc[0][2] += a0 * w2; acc[0][3] += a0 * w3;
            acc[1][0] += a1 * w0; acc[1][1] += a1 * w1; acc[1][2] += a1 * w2; acc[1][3] += a1 * w3;
            acc[2][0] += a2 * w0; acc[2][1] += a2 * w1; acc[2][2] += a2 * w2; acc[2][3] += a2 * w3;
            acc[3][0] += a3 * w0; acc[3][1] += a3 * w1; acc[3][2] += a3 * w2; acc[3][3] += a3 * w3;
        }
        __syncthreads();
    }

#pragma unroll
    for (int i = 0; i < 4; ++i) {
        int gm = m0 + ty * 4 + i;
        int orow;
        if (MODE == 0) orow = gm;
        else {
            int bb = gm >> 9;
            int tt = gm & (TSEQ - 1);
            orow = (MODE == 1 ? tt : (TSEQ - 1 - tt)) * NB + bb;
        }
#pragma unroll
        for (int j = 0; j < 4; ++j) {
            int gn = n0 + tx * 4 + j;
            if (gn < N) {
                float bias = (b1 ? b1[gn] : 0.f) + (b2 ? b2[gn] : 0.f);
                C[(size_t)orow * ldc + gn] = acc[i][j] + bias;
            }
        }
    }
}

// ---------------------------------------------------------------------------
// f32 GEMM, 128x128 tile, 8x8 microtile (64 FMA : 4 vector LDS reads per kk).
// Requires M%128==0, N%128==0, K%16==0.
// ---------------------------------------------------------------------------
template <int MODE>
__global__ __launch_bounds__(256) void gemm_nt_big(
    const float* __restrict__ A, int lda,
    const float* __restrict__ W, int ldw,
    const float* __restrict__ b1, const float* __restrict__ b2,
    float* __restrict__ C, int ldc, int K)
{
    __shared__ float As[16][132];
    __shared__ float Ws[16][132];
    const int tid = threadIdx.x;
    const int m0 = blockIdx.x * 128;
    const int n0 = blockIdx.y * 128;
    const int tx = tid & 15, ty = tid >> 4;
    const int lrow = tid >> 1, lk = (tid & 1) * 8;
    float acc[8][8] = {};

    for (int k0 = 0; k0 < K; k0 += 16) {
        float4 a0v = *(const float4*)(A + (size_t)(m0 + lrow) * lda + k0 + lk);
        float4 a1v = *(const float4*)(A + (size_t)(m0 + lrow) * lda + k0 + lk + 4);
        float4 w0v = *(const float4*)(W + (size_t)(n0 + lrow) * ldw + k0 + lk);
        float4 w1v = *(const float4*)(W + (size_t)(n0 + lrow) * ldw + k0 + lk + 4);
        As[lk + 0][lrow] = a0v.x; As[lk + 1][lrow] = a0v.y;
        As[lk + 2][lrow] = a0v.z; As[lk + 3][lrow] = a0v.w;
        As[lk + 4][lrow] = a1v.x; As[lk + 5][lrow] = a1v.y;
        As[lk + 6][lrow] = a1v.z; As[lk + 7][lrow] = a1v.w;
        Ws[lk + 0][lrow] = w0v.x; Ws[lk + 1][lrow] = w0v.y;
        Ws[lk + 2][lrow] = w0v.z; Ws[lk + 3][lrow] = w0v.w;
        Ws[lk + 4][lrow] = w1v.x; Ws[lk + 5][lrow] = w1v.y;
        Ws[lk + 6][lrow] = w1v.z; Ws[lk + 7][lrow] = w1v.w;
        __syncthreads();
#pragma unroll
        for (int kk = 0; kk < 16; ++kk) {
            float a[8], w[8];
#pragma unroll
            for (int i = 0; i < 8; ++i) a[i] = As[kk][ty * 8 + i];
#pragma unroll
            for (int j = 0; j < 8; ++j) w[j] = Ws[kk][tx * 8 + j];
#pragma unroll
            for (int i = 0; i < 8; ++i)
#pragma unroll
                for (int j = 0; j < 8; ++j)
                    acc[i][j] += a[i] * w[j];
        }
        __syncthreads();
    }

#pragma unroll
    for (int i = 0; i < 8; ++i) {
        int gm = m0 + ty * 8 + i;
        int orow;
        if (MODE == 0) orow = gm;
        else {
            int bb = gm >> 9;
            int tt = gm & (TSEQ - 1);
            orow = (MODE == 1 ? tt : (TSEQ - 1 - tt)) * NB + bb;
        }
        float* crow = C + (size_t)orow * ldc + n0 + tx * 8;
#pragma unroll
        for (int j = 0; j < 8; ++j) {
            int gn = n0 + tx * 8 + j;
            float bias = (b1 ? b1[gn] : 0.f) + (b2 ? b2[gn] : 0.f);
            crow[j] = acc[i][j] + bias;
        }
    }
}

// ---------------------------------------------------------------------------
// Encoder LSTM scan (unchanged).
// ---------------------------------------------------------------------------
__global__ __launch_bounds__(512) void enc_scan(
    const float* __restrict__ Gf, const float* __restrict__ Gr,
    const float* __restrict__ Whh_f, const float* __restrict__ Whh_r,
    float* __restrict__ hs_ctx)
{
    const int dir = blockIdx.x & 1;
    const int b = blockIdx.x >> 1;
    const float* __restrict__ G = dir ? Gr : Gf;
    const float* __restrict__ Whh = dir ? Whh_r : Whh_f;
    const int j = threadIdx.x;

    __shared__ float4 h4[H2E / 4];
    __shared__ float gates[4 * H2E];
    float* h_s = (float*)h4;

    float4 w[32];
#pragma unroll
    for (int k = 0; k < 32; ++k)
        w[k] = *(const float4*)(Whh + (size_t)j * H2E + k * 4);

    float c = 0.f;
    if (j < H2E) h_s[j] = 0.f;
    __syncthreads();

    for (int t = 0; t < TSEQ; ++t) {
        const float* grow = G + ((size_t)t * NB + b) * 512;
        float acc = grow[j];
#pragma unroll
        for (int k = 0; k < 32; ++k) {
            float4 hv = h4[k];
            acc += w[k].x * hv.x + w[k].y * hv.y + w[k].z * hv.z + w[k].w * hv.w;
        }
        gates[j] = acc;
        __syncthreads();
        if (j < H2E) {
            float ig = sigf(gates[j]);
            float fg = sigf(gates[j + H2E]);
            float gg = tanhfast(gates[j + 2 * H2E]);
            float og = sigf(gates[j + 3 * H2E]);
            c = fg * c + ig * gg;
            float h = og * tanhfast(c);
            h_s[j] = h;
            int tout = dir ? (TSEQ - 1 - t) : t;
            hs_ctx[((size_t)b * TSEQ + tout) * 512 + dir * H2E + j] = h;
        }
        __syncthreads();
    }
}

// ---------------------------------------------------------------------------
// Fused additive-attention scores + softmax (unchanged).
// ---------------------------------------------------------------------------
__global__ __launch_bounds__(256) void attn_w(
    const float* __restrict__ qp, const float* __restrict__ kp,
    const int* __restrict__ mask, const float* __restrict__ fc2,
    float* __restrict__ wout)
{
    const int bi = blockIdx.x;
    const int b = bi >> 9;
    const int tid = threadIdx.x;
    __shared__ float kps[TSEQ * 11];
    __shared__ float red[8];

    const float* kpb = kp + (size_t)b * TSEQ * 10;
    for (int idx = tid; idx < TSEQ * 10; idx += 256) {
        int j = idx / 10, xx = idx - j * 10;
        kps[j * 11 + xx] = kpb[idx];
    }
    float q[10], vv[10];
#pragma unroll
    for (int xx = 0; xx < 10; ++xx) {
        q[xx] = qp[(size_t)bi * 10 + xx];
        vv[xx] = fc2[xx];
    }
    __syncthreads();

    float a[2];
#pragma unroll
    for (int jj = 0; jj < 2; ++jj) {
        int j = tid + jj * 256;
        float s = 0.f;
#pragma unroll
        for (int xx = 0; xx < 10; ++xx)
            s += vv[xx] * tanhfast(q[xx] + kps[j * 11 + xx]);
        if (mask[(size_t)b * TSEQ + j] == 0) s = -1e30f;
        a[jj] = s;
    }

    float m = fmaxf(a[0], a[1]);
#pragma unroll
    for (int o = 32; o >= 1; o >>= 1) m = fmaxf(m, __shfl_xor(m, o));
    if ((tid & 63) == 0) red[tid >> 6] = m;
    __syncthreads();
    m = fmaxf(fmaxf(red[0], red[1]), fmaxf(red[2], red[3]));

    float e0 = __expf(a[0] - m), e1 = __expf(a[1] - m);
    float s = e0 + e1;
#pragma unroll
    for (int o = 32; o >= 1; o >>= 1) s += __shfl_xor(s, o);
    if ((tid & 63) == 0) red[4 + (tid >> 6)] = s;
    __syncthreads();
    s = (red[4] + red[5]) + (red[6] + red[7]);
    float inv = 1.0f / s;
    wout[(size_t)bi * TSEQ + tid] = e0 * inv;
    wout[(size_t)bi * TSEQ + tid + 256] = e1 * inv;
}

// ---------------------------------------------------------------------------
// Batched NN GEMM: ctx = w @ hs (unchanged).
// ---------------------------------------------------------------------------
__global__ __launch_bounds__(256) void bgemm_nn(
    const float* __restrict__ Wmat,
    float* __restrict__ hs_ctx)
{
    __shared__ float As[16][68];
    __shared__ float Bs[16][68];
    const int tid = threadIdx.x;
    const int b = blockIdx.z;
    const int i0 = blockIdx.x * 64;
    const int d0 = blockIdx.y * 64;
    const int tx = tid & 15, ty = tid >> 4;
    float acc[4][4] = {};
    const float* Ab = Wmat + (size_t)b * TSEQ * TSEQ;
    const float* Bb = hs_ctx + (size_t)b * TSEQ * 512;

    for (int k0 = 0; k0 < TSEQ; k0 += 16) {
        {
            int r = tid >> 2, kq = (tid & 3) * 4;
            float4 v = *(const float4*)(Ab + (size_t)(i0 + r) * TSEQ + k0 + kq);
            As[kq + 0][r] = v.x; As[kq + 1][r] = v.y; As[kq + 2][r] = v.z; As[kq + 3][r] = v.w;
        }
        {
            int kk = tid >> 4, dq = (tid & 15) * 4;
            float4 v = *(const float4*)(Bb + (size_t)(k0 + kk) * 512 + d0 + dq);
            *(float4*)&Bs[kk][dq] = v;
        }
        __syncthreads();
#pragma unroll
        for (int kk = 0; kk < 16; ++kk) {
            float a0 = As[kk][ty * 4 + 0], a1 = As[kk][ty * 4 + 1];
            float a2 = As[kk][ty * 4 + 2], a3 = As[kk][ty * 4 + 3];
            float b0 = Bs[kk][tx * 4 + 0], b1 = Bs[kk][tx * 4 + 1];
            float b2 = Bs[kk][tx * 4 + 2], b3 = Bs[kk][tx * 4 + 3];
            acc[0][0] += a0 * b0; acc[0][1] += a0 * b1; acc[0][2] += a0 * b2; acc[0][3] += a0 * b3;
            acc[1][0] += a1 * b0; acc[1][1] += a1 * b1; acc[1][2] += a1 * b2; acc[1][3] += a1 * b3;
            acc[2][0] += a2 * b0; acc[2][1] += a2 * b1; acc[2][2] += a2 * b2; acc[2][3] += a2 * b3;
            acc[3][0] += a3 * b0; acc[3][1] += a3 * b1; acc[3][2] += a3 * b2; acc[3][3] += a3 * b3;
        }
        __syncthreads();
    }
#pragma unroll
    for (int i = 0; i < 4; ++i)
#pragma unroll
        for (int j = 0; j < 4; ++j)
            hs_ctx[((size_t)b * TSEQ + i0 + ty * 4 + i) * 512 + 256 + d0 + tx * 4 + j] = acc[i][j];
}

// ---------------------------------------------------------------------------
// Decoder init (unchanged): clear all tags, seed h(-1) tag=1 parity 0.
// ---------------------------------------------------------------------------
__global__ __launch_bounds__(256) void dec_init4(
    const float* __restrict__ hs_ctx, ull* hbuf, ull* lbuf)
{
    const int gid = blockIdx.x * 256 + threadIdx.x;
    for (int idx = gid; idx < 32768; idx += 16 * 256) {
        ull v = 0ull;
        if (idx < 8192) {
            int b = idx >> 8, u = idx & 255;
            float hv = hs_ctx[((size_t)b * TSEQ + (TSEQ - 1)) * 512 + u];
            v = (1ull << 32) | (ull)__float_as_uint(hv);
        }
        ull* dst = (idx < 16384) ? (hbuf + idx) : (lbuf + (idx - 16384));
        __hip_atomic_store(dst, v, __ATOMIC_RELAXED, __HIP_MEMORY_SCOPE_AGENT);
    }
}

// ---------------------------------------------------------------------------
// Decoder scan v9 = v7(scan6) with ALIGNED, quad-odd weight rows.
// wlds row stride 260 floats = 1040 B: 16B-aligned (b128 legal) and 1040/16=65
// odd -> lane rr's b128 quad = (rr+i)&7 -> all 8 quads per 8 lanes ->
// conflict-free at the 8-cycle hardware minimum. h reads stay wave-uniform
// ds_read_b128 broadcasts. Tag sync / wave1 y-path / finalize = validated v6.
// ---------------------------------------------------------------------------
__global__ __launch_bounds__(256) void dec_scan8(
    const float* __restrict__ Gd,     // (T, NB, 1024), biases folded
    const float* __restrict__ Whh,    // (1024, 256)
    const float* __restrict__ Wih,    // (1024, 272); cols 256:272 multiply y
    const float* __restrict__ lin_w,  // (16, 256)
    const float* __restrict__ lin_b,  // (16,)
    ull* hbuf,                        // (2, NB, 256) tagged h
    ull* lbuf,                        // (2, NB, 256) tagged logit partials
    float* __restrict__ out)          // (NB, T, NC)
{
    const int tid = threadIdx.x;
    const int rg  = blockIdx.x & 15;
    const int bg  = blockIdx.x >> 4;
    const int kseg = tid >> 6;        // wave id 0..3
    const int rr   = tid & 63;        // gate row 0..63 within block
    const bool isw1 = (kseg == 1);
    const int ybb = (tid >> 4) & 3;
    const int ycls = tid & 15;

    __shared__ float wlds[64][260];   // Whh slice, aligned quad-odd stride
    __shared__ float hlds[4][260];    // h(t-1) per batch
    __shared__ float part[4][4][66];  // [bb][kseg][rr] gate partials
    __shared__ float ylds[4][17];     // y(t-1)
    __shared__ float hnew[4][17];     // new h slice (wave0-internal)
    __shared__ float linl[16][17];    // lin_w[cls][rg*16+u]
    __shared__ float wylds[64][17];   // y-weights for our 64 rows

    // ---- one-time staging ----
    for (int idx = tid; idx < 64 * 256; idx += 256) {
        int row = idx >> 8, c = idx & 255;
        int j = ((row >> 4) << 8) + rg * 16 + (row & 15);
        wlds[row][c] = Whh[(size_t)j * 256 + c];
    }
    {
        int r = tid >> 2, c0 = (tid & 3) * 4;
        int j = ((r >> 4) << 8) + rg * 16 + (r & 15);
        const float* src = Wih + (size_t)j * 272 + 256 + c0;
        wylds[r][c0 + 0] = src[0]; wylds[r][c0 + 1] = src[1];
        wylds[r][c0 + 2] = src[2]; wylds[r][c0 + 3] = src[3];
    }
    linl[tid >> 4][tid & 15] = lin_w[(tid >> 4) * 256 + rg * 16 + (tid & 15)];
    const float lb = lin_b[ycls];
    const int jrow = ((rr >> 4) << 8) + rg * 16 + (rr & 15);
    float cstate = 0.f;
    __syncthreads();

    for (int t = 0; t <= TSEQ; ++t) {
        const unsigned want = (unsigned)(t + 1);
        const ull* hsrc = hbuf + (size_t)(t & 1) * 8192 + (size_t)bg * 1024;
        const ull* lsrc = lbuf + (size_t)(t & 1) * 8192 + (size_t)bg * 1024;

        // Gd prefetch (h-independent), wave0 only
        float gv0 = 0.f, gv1 = 0.f, gv2 = 0.f, gv3 = 0.f;
        if (kseg == 0 && t < TSEQ) {
            const float* gb = Gd + ((size_t)t * NB + bg * 4) * 1024 + jrow;
            gv0 = gb[0]; gv1 = gb[1024]; gv2 = gb[2048]; gv3 = gb[3072];
        }
        __builtin_amdgcn_sched_barrier(0);

        // ---- wave1: y-path (poll tagged logit partials, softmax, out) ----
        if (isw1) {
            float yv = 0.f;
            if (t > 0) {
                float lsum;
                for (;;) {
                    lsum = lb;
                    bool ok = true;
#pragma unroll
                    for (int r = 0; r < 16; ++r) {
                        ull lv = __hip_atomic_load(lsrc + ybb * 256 + r * 16 + ycls,
                                                   __ATOMIC_RELAXED, __HIP_MEMORY_SCOPE_AGENT);
                        ok &= ((unsigned)(lv >> 32) == want);
                        lsum += __uint_as_float((unsigned)lv);
                    }
                    if (ok) break;
                    __builtin_amdgcn_s_sleep(1);
                }
                float m = lsum;
#pragma unroll
                for (int o = 1; o < 16; o <<= 1) m = fmaxf(m, __shfl_xor(m, o, 16));
                float e = __expf(lsum - m);
                float ss = e;
#pragma unroll
                for (int o = 1; o < 16; o <<= 1) ss += __shfl_xor(ss, o, 16);
                yv = e / ss;
                if (rg == 0)
                    out[(((size_t)(bg * 4 + ybb)) * TSEQ + (t - 1)) * NC + ycls] = yv;
            }
            ylds[ybb][ycls] = yv;
        }

        // ---- all threads: verify + load own 4 tagged h-words ----
        {
            ull h0, h1, h2, h3;
            for (;;) {
                h0 = __hip_atomic_load(hsrc + tid,       __ATOMIC_RELAXED, __HIP_MEMORY_SCOPE_AGENT);
                h1 = __hip_atomic_load(hsrc + tid + 256, __ATOMIC_RELAXED, __HIP_MEMORY_SCOPE_AGENT);
                h2 = __hip_atomic_load(hsrc + tid + 512, __ATOMIC_RELAXED, __HIP_MEMORY_SCOPE_AGENT);
                h3 = __hip_atomic_load(hsrc + tid + 768, __ATOMIC_RELAXED, __HIP_MEMORY_SCOPE_AGENT);
                if (((unsigned)(h0 >> 32) == want) && ((unsigned)(h1 >> 32) == want) &&
                    ((unsigned)(h2 >> 32) == want) && ((unsigned)(h3 >> 32) == want))
                    break;
                __builtin_amdgcn_s_sleep(1);
            }
            hlds[0][tid] = __uint_as_float((unsigned)h0);
            hlds[1][tid] = __uint_as_float((unsigned)h1);
            hlds[2][tid] = __uint_as_float((unsigned)h2);
            hlds[3][tid] = __uint_as_float((unsigned)h3);
        }
        __syncthreads();   // hlds + ylds ready

        if (t == TSEQ) break;

        // ---- gate partials: conflict-free b128 w-rows x broadcast h ----
        {
            float a0 = gv0, a1 = gv1, a2 = gv2, a3 = gv3;
            const f32x4* wrow = (const f32x4*)&wlds[rr][kseg * 64];
#pragma unroll
            for (int i = 0; i < 16; ++i) {
                const f32x4 w = wrow[i];
                const int kc = kseg * 64 + i * 4;
                f32x4 p0 = *(const f32x4*)&hlds[0][kc];
                f32x4 p1 = *(const f32x4*)&hlds[1][kc];
                f32x4 p2 = *(const f32x4*)&hlds[2][kc];
                f32x4 p3 = *(const f32x4*)&hlds[3][kc];
                a0 += w.x * p0.x + w.y * p0.y + w.z * p0.z + w.w * p0.w;
                a1 += w.x * p1.x + w.y * p1.y + w.z * p1.z + w.w * p1.w;
                a2 += w.x * p2.x + w.y * p2.y + w.z * p2.z + w.w * p2.w;
                a3 += w.x * p3.x + w.y * p3.y + w.z * p3.z + w.w * p3.w;
            }
            part[0][kseg][rr] = a0;
            part[1][kseg][rr] = a1;
            part[2][kseg][rr] = a2;
            part[3][kseg][rr] = a3;
        }
        __syncthreads();   // part ready

        // ---- finalize (wave0): ksegs + y-term, nonlinearity, publish ----
        if (tid < 64) {
            const int bb = ybb, u = ycls;
            float g[4];
#pragma unroll
            for (int q = 0; q < 4; ++q) {
                const int r = q * 16 + u;
                float s = part[bb][0][r] + part[bb][1][r]
                        + part[bb][2][r] + part[bb][3][r];
#pragma unroll
                for (int c = 0; c < 16; ++c)
                    s += wylds[r][c] * ylds[bb][c];
                g[q] = s;
            }
            float ig = sigf(g[0]), fg = sigf(g[1]);
            float gv = tanhfast(g[2]), og = sigf(g[3]);
            cstate = fg * cstate + ig * gv;
            float h = og * tanhfast(cstate);
            hnew[bb][u] = h;
            const ull tagbits = ((ull)(unsigned)(t + 2)) << 32;
            const size_t oidx = (size_t)((t + 1) & 1) * 8192
                              + (size_t)(bg * 4 + bb) * 256 + rg * 16 + u;
            __hip_atomic_store(hbuf + oidx, tagbits | (ull)__float_as_uint(h),
                               __ATOMIC_RELAXED, __HIP_MEMORY_SCOPE_AGENT);
            float lp = 0.f;
#pragma unroll
            for (int u2 = 0; u2 < 16; ++u2)
                lp += linl[u][u2] * hnew[bb][u2];
            __hip_atomic_store(lbuf + oidx, tagbits | (ull)__float_as_uint(lp),
                               __ATOMIC_RELAXED, __HIP_MEMORY_SCOPE_AGENT);
        }
        // no trailing barrier: next-step verify self-gates on our publish
    }
}

// ---------------------------------------------------------------------------
extern "C" void kernel_launch(void* const* d_in, const int* in_sizes, int n_in,
                              void* d_out, int out_size, void* d_ws, size_t ws_size,
                              hipStream_t stream)
{
    const float* x     = (const float*)d_in[0];
    const int*   mask  = (const int*)d_in[1];
    const float* Wih_f = (const float*)d_in[2];
    const float* Whh_f = (const float*)d_in[3];
    const float* bih_f = (const float*)d_in[4];
    const float* bhh_f = (const float*)d_in[5];
    const float* Wih_r = (const float*)d_in[6];
    const float* Whh_r = (const float*)d_in[7];
    const float* bih_r = (const float*)d_in[8];
    const float* bhh_r = (const float*)d_in[9];
    const float* fc1_w = (const float*)d_in[10];
    const float* fc2_w = (const float*)d_in[11];
    const float* fc3_w = (const float*)d_in[12];
    const float* fc3_b = (const float*)d_in[13];
    const float* Wih_d = (const float*)d_in[14];
    const float* Whh_d = (const float*)d_in[15];
    const float* bih_d = (const float*)d_in[16];
    const float* bhh_d = (const float*)d_in[17];
    const float* lin_w = (const float*)d_in[18];
    const float* lin_b = (const float*)d_in[19];

    float* ws = (float*)d_ws;
    float* Gf   = ws;
    float* Gr   = ws + 8388608;
    float* hs   = ws + 16777216;
    float* wat  = ws + 25165824;
    float* qp   = ws + 33554432;
    float* kp   = ws + 33718272;
    float* Gd   = ws;
    float* yenc = wat;
    ull* hbuf = (ull*)(wat + 4194304);
    ull* lbuf = hbuf + 16384;

    float* outp = (float*)d_out;
    const int M = NB * TSEQ;       // 16384
    dim3 blk(256);

    // 1-2. encoder input projections (128x128 tiles)
    gemm_nt_big<1><<<dim3(M / 128, 4), blk, 0, stream>>>(x, DB, Wih_f, DB, bih_f, bhh_f, Gf, 512, DB);
    gemm_nt_big<2><<<dim3(M / 128, 4), blk, 0, stream>>>(x, DB, Wih_r, DB, bih_r, bhh_r, Gr, 512, DB);
    // 3. bidirectional recurrence
    enc_scan<<<dim3(64), dim3(512), 0, stream>>>(Gf, Gr, Whh_f, Whh_r, hs);
    // 4-5. q/k projections (tiny N, 64x64)
    gemm_nt<0><<<dim3(M / 64, 1), blk, 0, stream>>>(hs, 512, fc1_w, 512, nullptr, nullptr, qp, 10, 10, 256);
    gemm_nt<0><<<dim3(M / 64, 1), blk, 0, stream>>>(hs, 512, fc1_w + 256, 512, nullptr, nullptr, kp, 10, 10, 256);
    // 6. attention scores + softmax
    attn_w<<<dim3(M), blk, 0, stream>>>(qp, kp, mask, fc2_w, wat);
    // 7. ctx = w @ hs
    bgemm_nn<<<dim3(8, 4, NB), blk, 0, stream>>>(wat, hs);
    // 8. y_enc (128x128)
    gemm_nt_big<0><<<dim3(M / 128, 2), blk, 0, stream>>>(hs, 512, fc3_w, 512, fc3_b, nullptr, yenc, 256, 512);
    // 8.5 decoder comm init
    dec_init4<<<dim3(16), blk, 0, stream>>>(hs, hbuf, lbuf);
    // 9. decoder input projection (128x128)
    gemm_nt_big<1><<<dim3(M / 128, 8), blk, 0, stream>>>(yenc, 256, Wih_d, 272, bih_d, bhh_d, Gd, 1024, 256);
    // 10. decoder recurrence (aligned conflict-free LDS weights + tag sync)
    dec_scan8<<<dim3(128), blk, 0, stream>>>(Gd, Whh_d, Wih_d, lin_w, lin_b, hbuf, lbuf, outp);
}

// Round 11
// 3080.604 us; speedup vs baseline: 1.2091x; 1.1078x over previous
//
#include <hip/hip_runtime.h>

// Problem constants
#define TSEQ 512
#define NB   32     // batch
#define DB   768    // d_bert
#define H2E  128    // encoder hidden per dir
#define DL   256    // d_lstm
#define NC   16     // n_class

typedef unsigned long long ull;
typedef float f32x4 __attribute__((ext_vector_type(4)));
typedef short bf16x8 __attribute__((ext_vector_type(8)));
typedef unsigned short u16x8 __attribute__((ext_vector_type(8)));

__device__ __forceinline__ float sigf(float x) { return 1.0f / (1.0f + __expf(-x)); }
__device__ __forceinline__ float tanhfast(float x) { return 1.0f - 2.0f / (1.0f + __expf(2.0f * x)); }

// split f32 -> hi bf16 (RNE) + lo bf16 (RNE of residual)
__device__ __forceinline__ void cvt_split(float a, unsigned short& hi, unsigned short& lo) {
    unsigned u = __float_as_uint(a);
    unsigned h = (u + 0x7FFFu + ((u >> 16) & 1u)) >> 16;
    float hf = __uint_as_float(h << 16);
    float d = a - hf;
    unsigned ud = __float_as_uint(d);
    unsigned l = (ud + 0x7FFFu + ((ud >> 16) & 1u)) >> 16;
    hi = (unsigned short)h;
    lo = (unsigned short)l;
}

// ---------------------------------------------------------------------------
// Split-bf16 MFMA GEMM: C[remap(m), n] = sum_k A[m,k] * W[n,k] (+ b1 + b2).
// 128x128 tile, 4 waves (2x2), each wave 64x64 = 4x4 fragments of 16x16x32.
// f32 operands split hi/lo during staging; 3 MFMAs per fragment product.
// Requires M%128==0, N%128==0, K%32==0.
// MODE 0: direct. MODE 1: m=b*T+t -> row t*NB+b. MODE 2: -> (T-1-t)*NB+b.
// ---------------------------------------------------------------------------
#define LDST 40   // LDS row stride (ushorts): 80B = 16B-aligned, bank-spread
template <int MODE>
__global__ __launch_bounds__(256) void gemm_mfma(
    const float* __restrict__ A, int lda,
    const float* __restrict__ W, int ldw,
    const float* __restrict__ b1, const float* __restrict__ b2,
    float* __restrict__ C, int ldc, int K)
{
    __shared__ unsigned short Ah[128][LDST];
    __shared__ unsigned short Al[128][LDST];
    __shared__ unsigned short Wh[128][LDST];
    __shared__ unsigned short Wl[128][LDST];

    const int tid = threadIdx.x;
    const int m0 = blockIdx.x * 128;
    const int n0 = blockIdx.y * 128;
    const int wave = tid >> 6, lane = tid & 63;
    const int wr = wave >> 1, wc = wave & 1;
    const int fr = lane & 15;      // fragment row/col index
    const int fq = lane >> 4;      // k-octet
    const int srow = tid >> 1, skoff = (tid & 1) * 16;   // staging map

    f32x4 acc[4][4] = {};

    for (int k0 = 0; k0 < K; k0 += 32) {
        __syncthreads();   // protect LDS from previous iteration's readers
        // ---- stage A rows (16 f32 -> hi/lo bf16) ----
        {
            const float* src = A + (size_t)(m0 + srow) * lda + k0 + skoff;
            u16x8 vh0, vh1, vl0, vl1;
#pragma unroll
            for (int e = 0; e < 8; ++e) {
                unsigned short h, l;
                cvt_split(src[e], h, l);
                vh0[e] = h; vl0[e] = l;
                cvt_split(src[e + 8], h, l);
                vh1[e] = h; vl1[e] = l;
            }
            *(u16x8*)&Ah[srow][skoff]     = vh0;
            *(u16x8*)&Ah[srow][skoff + 8] = vh1;
            *(u16x8*)&Al[srow][skoff]     = vl0;
            *(u16x8*)&Al[srow][skoff + 8] = vl1;
        }
        // ---- stage W rows ----
        {
            const float* src = W + (size_t)(n0 + srow) * ldw + k0 + skoff;
            u16x8 vh0, vh1, vl0, vl1;
#pragma unroll
            for (int e = 0; e < 8; ++e) {
                unsigned short h, l;
                cvt_split(src[e], h, l);
                vh0[e] = h; vl0[e] = l;
                cvt_split(src[e + 8], h, l);
                vh1[e] = h; vl1[e] = l;
            }
            *(u16x8*)&Wh[srow][skoff]     = vh0;
            *(u16x8*)&Wh[srow][skoff + 8] = vh1;
            *(u16x8*)&Wl[srow][skoff]     = vl0;
            *(u16x8*)&Wl[srow][skoff + 8] = vl1;
        }
        __syncthreads();

        // ---- fragments ----
        bf16x8 ah[4], al[4], bh[4], bl[4];
#pragma unroll
        for (int i = 0; i < 4; ++i) {
            const int r = wr * 64 + i * 16 + fr;
            ah[i] = *(const bf16x8*)&Ah[r][fq * 8];
            al[i] = *(const bf16x8*)&Al[r][fq * 8];
        }
#pragma unroll
        for (int j = 0; j < 4; ++j) {
            const int r = wc * 64 + j * 16 + fr;
            bh[j] = *(const bf16x8*)&Wh[r][fq * 8];
            bl[j] = *(const bf16x8*)&Wl[r][fq * 8];
        }
#pragma unroll
        for (int i = 0; i < 4; ++i)
#pragma unroll
            for (int j = 0; j < 4; ++j) {
                acc[i][j] = __builtin_amdgcn_mfma_f32_16x16x32_bf16(ah[i], bh[j], acc[i][j], 0, 0, 0);
                acc[i][j] = __builtin_amdgcn_mfma_f32_16x16x32_bf16(ah[i], bl[j], acc[i][j], 0, 0, 0);
                acc[i][j] = __builtin_amdgcn_mfma_f32_16x16x32_bf16(al[i], bh[j], acc[i][j], 0, 0, 0);
            }
    }

    // ---- epilogue: C/D mapping col=lane&15, row=(lane>>4)*4+reg ----
#pragma unroll
    for (int i = 0; i < 4; ++i) {
#pragma unroll
        for (int r = 0; r < 4; ++r) {
            int gm = m0 + wr * 64 + i * 16 + fq * 4 + r;
            int orow;
            if (MODE == 0) orow = gm;
            else {
                int bb = gm >> 9;
                int tt = gm & (TSEQ - 1);
                orow = (MODE == 1 ? tt : (TSEQ - 1 - tt)) * NB + bb;
            }
            float* crow = C + (size_t)orow * ldc;
#pragma unroll
            for (int j = 0; j < 4; ++j) {
                int gn = n0 + wc * 64 + j * 16 + fr;
                float bias = (b1 ? b1[gn] : 0.f) + (b2 ? b2[gn] : 0.f);
                crow[gn] = acc[i][j][r] + bias;
            }
        }
    }
}

// ---------------------------------------------------------------------------
// f32 GEMM, 64x64 tile (tiny-N q/k projections only).
// ---------------------------------------------------------------------------
template <int MODE>
__global__ __launch_bounds__(256) void gemm_nt(
    const float* __restrict__ A, int lda,
    const float* __restrict__ W, int ldw,
    const float* __restrict__ b1, const float* __restrict__ b2,
    float* __restrict__ C, int ldc, int N, int K)
{
    __shared__ float As[16][68];
    __shared__ float Ws[16][68];
    const int tid = threadIdx.x;
    const int m0 = blockIdx.x * 64;
    const int n0 = blockIdx.y * 64;
    const int tx = tid & 15, ty = tid >> 4;
    const int lrow = tid >> 2;
    const int lk = (tid & 3) * 4;
    float acc[4][4] = {};

    for (int k0 = 0; k0 < K; k0 += 16) {
        float4 av = *(const float4*)(A + (size_t)(m0 + lrow) * lda + k0 + lk);
        float4 wv = make_float4(0.f, 0.f, 0.f, 0.f);
        if (n0 + lrow < N)
            wv = *(const float4*)(W + (size_t)(n0 + lrow) * ldw + k0 + lk);
        As[lk + 0][lrow] = av.x; As[lk + 1][lrow] = av.y;
        As[lk + 2][lrow] = av.z; As[lk + 3][lrow] = av.w;
        Ws[lk + 0][lrow] = wv.x; Ws[lk + 1][lrow] = wv.y;
        Ws[lk + 2][lrow] = wv.z; Ws[lk + 3][lrow] = wv.w;
        __syncthreads();
#pragma unroll
        for (int kk = 0; kk < 16; ++kk) {
            float a0 = As[kk][ty * 4 + 0], a1 = As[kk][ty * 4 + 1];
            float a2 = As[kk][ty * 4 + 2], a3 = As[kk][ty * 4 + 3];
            float w0 = Ws[kk][tx * 4 + 0], w1 = Ws[kk][tx * 4 + 1];
            float w2 = Ws[kk][tx * 4 + 2], w3 = Ws[kk][tx * 4 + 3];
            acc[0][0] += a0 * w0; acc[0][1] += a0 * w1; acc[0][2] += a0 * w2; acc[0][3] += a0 * w3;
            acc[1][0] += a1 * w0; acc[1][1] += a1 * w1; acc[1][2] += a1 * w2; acc[1][3] += a1 * w3;
            acc[2][0] += a2 * w0; acc[2][1] += a2 * w1; acc[2][2] += a2 * w2; acc[2][3] += a2 * w3;
            acc[3][0] += a3 * w0; acc[3][1] += a3 * w1; acc[3][2] += a3 * w2; acc[3][3] += a3 * w3;
        }
        __syncthreads();
    }

#pragma unroll
    for (int i = 0; i < 4; ++i) {
        int gm = m0 + ty * 4 + i;
        int orow;
        if (MODE == 0) orow = gm;
        else {
            int bb = gm >> 9;
            int tt = gm & (TSEQ - 1);
            orow = (MODE == 1 ? tt : (TSEQ - 1 - tt)) * NB + bb;
        }
#pragma unroll
        for (int j = 0; j < 4; ++j) {
            int gn = n0 + tx * 4 + j;
            if (gn < N) {
                float bias = (b1 ? b1[gn] : 0.f) + (b2 ? b2[gn] : 0.f);
                C[(size_t)orow * ldc + gn] = acc[i][j] + bias;
            }
        }
    }
}

// ---------------------------------------------------------------------------
// Encoder LSTM scan (unchanged).
// ---------------------------------------------------------------------------
__global__ __launch_bounds__(512) void enc_scan(
    const float* __restrict__ Gf, const float* __restrict__ Gr,
    const float* __restrict__ Whh_f, const float* __restrict__ Whh_r,
    float* __restrict__ hs_ctx)
{
    const int dir = blockIdx.x & 1;
    const int b = blockIdx.x >> 1;
    const float* __restrict__ G = dir ? Gr : Gf;
    const float* __restrict__ Whh = dir ? Whh_r : Whh_f;
    const int j = threadIdx.x;

    __shared__ float4 h4[H2E / 4];
    __shared__ float gates[4 * H2E];
    float* h_s = (float*)h4;

    float4 w[32];
#pragma unroll
    for (int k = 0; k < 32; ++k)
        w[k] = *(const float4*)(Whh + (size_t)j * H2E + k * 4);

    float c = 0.f;
    if (j < H2E) h_s[j] = 0.f;
    __syncthreads();

    for (int t = 0; t < TSEQ; ++t) {
        const float* grow = G + ((size_t)t * NB + b) * 512;
        float acc = grow[j];
#pragma unroll
        for (int k = 0; k < 32; ++k) {
            float4 hv = h4[k];
            acc += w[k].x * hv.x + w[k].y * hv.y + w[k].z * hv.z + w[k].w * hv.w;
        }
        gates[j] = acc;
        __syncthreads();
        if (j < H2E) {
            float ig = sigf(gates[j]);
            float fg = sigf(gates[j + H2E]);
            float gg = tanhfast(gates[j + 2 * H2E]);
            float og = sigf(gates[j + 3 * H2E]);
            c = fg * c + ig * gg;
            float h = og * tanhfast(c);
            h_s[j] = h;
            int tout = dir ? (TSEQ - 1 - t) : t;
            hs_ctx[((size_t)b * TSEQ + tout) * 512 + dir * H2E + j] = h;
        }
        __syncthreads();
    }
}

// ---------------------------------------------------------------------------
// Fused additive-attention scores + softmax (unchanged).
// ---------------------------------------------------------------------------
__global__ __launch_bounds__(256) void attn_w(
    const float* __restrict__ qp, const float* __restrict__ kp,
    const int* __restrict__ mask, const float* __restrict__ fc2,
    float* __restrict__ wout)
{
    const int bi = blockIdx.x;
    const int b = bi >> 9;
    const int tid = threadIdx.x;
    __shared__ float kps[TSEQ * 11];
    __shared__ float red[8];

    const float* kpb = kp + (size_t)b * TSEQ * 10;
    for (int idx = tid; idx < TSEQ * 10; idx += 256) {
        int j = idx / 10, xx = idx - j * 10;
        kps[j * 11 + xx] = kpb[idx];
    }
    float q[10], vv[10];
#pragma unroll
    for (int xx = 0; xx < 10; ++xx) {
        q[xx] = qp[(size_t)bi * 10 + xx];
        vv[xx] = fc2[xx];
    }
    __syncthreads();

    float a[2];
#pragma unroll
    for (int jj = 0; jj < 2; ++jj) {
        int j = tid + jj * 256;
        float s = 0.f;
#pragma unroll
        for (int xx = 0; xx < 10; ++xx)
            s += vv[xx] * tanhfast(q[xx] + kps[j * 11 + xx]);
        if (mask[(size_t)b * TSEQ + j] == 0) s = -1e30f;
        a[jj] = s;
    }

    float m = fmaxf(a[0], a[1]);
#pragma unroll
    for (int o = 32; o >= 1; o >>= 1) m = fmaxf(m, __shfl_xor(m, o));
    if ((tid & 63) == 0) red[tid >> 6] = m;
    __syncthreads();
    m = fmaxf(fmaxf(red[0], red[1]), fmaxf(red[2], red[3]));

    float e0 = __expf(a[0] - m), e1 = __expf(a[1] - m);
    float s = e0 + e1;
#pragma unroll
    for (int o = 32; o >= 1; o >>= 1) s += __shfl_xor(s, o);
    if ((tid & 63) == 0) red[4 + (tid >> 6)] = s;
    __syncthreads();
    s = (red[4] + red[5]) + (red[6] + red[7]);
    float inv = 1.0f / s;
    wout[(size_t)bi * TSEQ + tid] = e0 * inv;
    wout[(size_t)bi * TSEQ + tid + 256] = e1 * inv;
}

// ---------------------------------------------------------------------------
// Batched NN GEMM: ctx = w @ hs (unchanged).
// ---------------------------------------------------------------------------
__global__ __launch_bounds__(256) void bgemm_nn(
    const float* __restrict__ Wmat,
    float* __restrict__ hs_ctx)
{
    __shared__ float As[16][68];
    __shared__ float Bs[16][68];
    const int tid = threadIdx.x;
    const int b = blockIdx.z;
    const int i0 = blockIdx.x * 64;
    const int d0 = blockIdx.y * 64;
    const int tx = tid & 15, ty = tid >> 4;
    float acc[4][4] = {};
    const float* Ab = Wmat + (size_t)b * TSEQ * TSEQ;
    const float* Bb = hs_ctx + (size_t)b * TSEQ * 512;

    for (int k0 = 0; k0 < TSEQ; k0 += 16) {
        {
            int r = tid >> 2, kq = (tid & 3) * 4;
            float4 v = *(const float4*)(Ab + (size_t)(i0 + r) * TSEQ + k0 + kq);
            As[kq + 0][r] = v.x; As[kq + 1][r] = v.y; As[kq + 2][r] = v.z; As[kq + 3][r] = v.w;
        }
        {
            int kk = tid >> 4, dq = (tid & 15) * 4;
            float4 v = *(const float4*)(Bb + (size_t)(k0 + kk) * 512 + d0 + dq);
            *(float4*)&Bs[kk][dq] = v;
        }
        __syncthreads();
#pragma unroll
        for (int kk = 0; kk < 16; ++kk) {
            float a0 = As[kk][ty * 4 + 0], a1 = As[kk][ty * 4 + 1];
            float a2 = As[kk][ty * 4 + 2], a3 = As[kk][ty * 4 + 3];
            float b0 = Bs[kk][tx * 4 + 0], b1 = Bs[kk][tx * 4 + 1];
            float b2 = Bs[kk][tx * 4 + 2], b3 = Bs[kk][tx * 4 + 3];
            acc[0][0] += a0 * b0; acc[0][1] += a0 * b1; acc[0][2] += a0 * b2; acc[0][3] += a0 * b3;
            acc[1][0] += a1 * b0; acc[1][1] += a1 * b1; acc[1][2] += a1 * b2; acc[1][3] += a1 * b3;
            acc[2][0] += a2 * b0; acc[2][1] += a2 * b1; acc[2][2] += a2 * b2; acc[2][3] += a2 * b3;
            acc[3][0] += a3 * b0; acc[3][1] += a3 * b1; acc[3][2] += a3 * b2; acc[3][3] += a3 * b3;
        }
        __syncthreads();
    }
#pragma unroll
    for (int i = 0; i < 4; ++i)
#pragma unroll
        for (int j = 0; j < 4; ++j)
            hs_ctx[((size_t)b * TSEQ + i0 + ty * 4 + i) * 512 + 256 + d0 + tx * 4 + j] = acc[i][j];
}

// ---------------------------------------------------------------------------
// Decoder init (unchanged): clear all tags, seed h(-1) tag=1 parity 0.
// ---------------------------------------------------------------------------
__global__ __launch_bounds__(256) void dec_init4(
    const float* __restrict__ hs_ctx, ull* hbuf, ull* lbuf)
{
    const int gid = blockIdx.x * 256 + threadIdx.x;
    for (int idx = gid; idx < 32768; idx += 16 * 256) {
        ull v = 0ull;
        if (idx < 8192) {
            int b = idx >> 8, u = idx & 255;
            float hv = hs_ctx[((size_t)b * TSEQ + (TSEQ - 1)) * 512 + u];
            v = (1ull << 32) | (ull)__float_as_uint(hv);
        }
        ull* dst = (idx < 16384) ? (hbuf + idx) : (lbuf + (idx - 16384));
        __hip_atomic_store(dst, v, __ATOMIC_RELAXED, __HIP_MEMORY_SCOPE_AGENT);
    }
}

// ---------------------------------------------------------------------------
// Decoder scan (= best-known scan8, unchanged).
// ---------------------------------------------------------------------------
__global__ __launch_bounds__(256) void dec_scan8(
    const float* __restrict__ Gd,
    const float* __restrict__ Whh,
    const float* __restrict__ Wih,
    const float* __restrict__ lin_w,
    const float* __restrict__ lin_b,
    ull* hbuf, ull* lbuf,
    float* __restrict__ out)
{
    const int tid = threadIdx.x;
    const int rg  = blockIdx.x & 15;
    const int bg  = blockIdx.x >> 4;
    const int kseg = tid >> 6;
    const int rr   = tid & 63;
    const bool isw1 = (kseg == 1);
    const int ybb = (tid >> 4) & 3;
    const int ycls = tid & 15;

    __shared__ float wlds[64][260];
    __shared__ float hlds[4][260];
    __shared__ float part[4][4][66];
    __shared__ float ylds[4][17];
    __shared__ float hnew[4][17];
    __shared__ float linl[16][17];
    __shared__ float wylds[64][17];

    for (int idx = tid; idx < 64 * 256; idx += 256) {
        int row = idx >> 8, c = idx & 255;
        int j = ((row >> 4) << 8) + rg * 16 + (row & 15);
        wlds[row][c] = Whh[(size_t)j * 256 + c];
    }
    {
        int r = tid >> 2, c0 = (tid & 3) * 4;
        int j = ((r >> 4) << 8) + rg * 16 + (r & 15);
        const float* src = Wih + (size_t)j * 272 + 256 + c0;
        wylds[r][c0 + 0] = src[0]; wylds[r][c0 + 1] = src[1];
        wylds[r][c0 + 2] = src[2]; wylds[r][c0 + 3] = src[3];
    }
    linl[tid >> 4][tid & 15] = lin_w[(tid >> 4) * 256 + rg * 16 + (tid & 15)];
    const float lb = lin_b[ycls];
    const int jrow = ((rr >> 4) << 8) + rg * 16 + (rr & 15);
    float cstate = 0.f;
    __syncthreads();

    for (int t = 0; t <= TSEQ; ++t) {
        const unsigned want = (unsigned)(t + 1);
        const ull* hsrc = hbuf + (size_t)(t & 1) * 8192 + (size_t)bg * 1024;
        const ull* lsrc = lbuf + (size_t)(t & 1) * 8192 + (size_t)bg * 1024;

        float gv0 = 0.f, gv1 = 0.f, gv2 = 0.f, gv3 = 0.f;
        if (kseg == 0 && t < TSEQ) {
            const float* gb = Gd + ((size_t)t * NB + bg * 4) * 1024 + jrow;
            gv0 = gb[0]; gv1 = gb[1024]; gv2 = gb[2048]; gv3 = gb[3072];
        }
        __builtin_amdgcn_sched_barrier(0);

        if (isw1) {
            float yv = 0.f;
            if (t > 0) {
                float lsum;
                for (;;) {
                    lsum = lb;
                    bool ok = true;
#pragma unroll
                    for (int r = 0; r < 16; ++r) {
                        ull lv = __hip_atomic_load(lsrc + ybb * 256 + r * 16 + ycls,
                                                   __ATOMIC_RELAXED, __HIP_MEMORY_SCOPE_AGENT);
                        ok &= ((unsigned)(lv >> 32) == want);
                        lsum += __uint_as_float((unsigned)lv);
                    }
                    if (ok) break;
                    __builtin_amdgcn_s_sleep(1);
                }
                float m = lsum;
#pragma unroll
                for (int o = 1; o < 16; o <<= 1) m = fmaxf(m, __shfl_xor(m, o, 16));
                float e = __expf(lsum - m);
                float ss = e;
#pragma unroll
                for (int o = 1; o < 16; o <<= 1) ss += __shfl_xor(ss, o, 16);
                yv = e / ss;
                if (rg == 0)
                    out[(((size_t)(bg * 4 + ybb)) * TSEQ + (t - 1)) * NC + ycls] = yv;
            }
            ylds[ybb][ycls] = yv;
        }

        {
            ull h0, h1, h2, h3;
            for (;;) {
                h0 = __hip_atomic_load(hsrc + tid,       __ATOMIC_RELAXED, __HIP_MEMORY_SCOPE_AGENT);
                h1 = __hip_atomic_load(hsrc + tid + 256, __ATOMIC_RELAXED, __HIP_MEMORY_SCOPE_AGENT);
                h2 = __hip_atomic_load(hsrc + tid + 512, __ATOMIC_RELAXED, __HIP_MEMORY_SCOPE_AGENT);
                h3 = __hip_atomic_load(hsrc + tid + 768, __ATOMIC_RELAXED, __HIP_MEMORY_SCOPE_AGENT);
                if (((unsigned)(h0 >> 32) == want) && ((unsigned)(h1 >> 32) == want) &&
                    ((unsigned)(h2 >> 32) == want) && ((unsigned)(h3 >> 32) == want))
                    break;
                __builtin_amdgcn_s_sleep(1);
            }
            hlds[0][tid] = __uint_as_float((unsigned)h0);
            hlds[1][tid] = __uint_as_float((unsigned)h1);
            hlds[2][tid] = __uint_as_float((unsigned)h2);
            hlds[3][tid] = __uint_as_float((unsigned)h3);
        }
        __syncthreads();

        if (t == TSEQ) break;

        {
            float a0 = gv0, a1 = gv1, a2 = gv2, a3 = gv3;
            const f32x4* wrow = (const f32x4*)&wlds[rr][kseg * 64];
#pragma unroll
            for (int i = 0; i < 16; ++i) {
                const f32x4 w = wrow[i];
                const int kc = kseg * 64 + i * 4;
                f32x4 p0 = *(const f32x4*)&hlds[0][kc];
                f32x4 p1 = *(const f32x4*)&hlds[1][kc];
                f32x4 p2 = *(const f32x4*)&hlds[2][kc];
                f32x4 p3 = *(const f32x4*)&hlds[3][kc];
                a0 += w.x * p0.x + w.y * p0.y + w.z * p0.z + w.w * p0.w;
                a1 += w.x * p1.x + w.y * p1.y + w.z * p1.z + w.w * p1.w;
                a2 += w.x * p2.x + w.y * p2.y + w.z * p2.z + w.w * p2.w;
                a3 += w.x * p3.x + w.y * p3.y + w.z * p3.z + w.w * p3.w;
            }
            part[0][kseg][rr] = a0;
            part[1][kseg][rr] = a1;
            part[2][kseg][rr] = a2;
            part[3][kseg][rr] = a3;
        }
        __syncthreads();

        if (tid < 64) {
            const int bb = ybb, u = ycls;
            float g[4];
#pragma unroll
            for (int q = 0; q < 4; ++q) {
                const int r = q * 16 + u;
                float s = part[bb][0][r] + part[bb][1][r]
                        + part[bb][2][r] + part[bb][3][r];
#pragma unroll
                for (int c = 0; c < 16; ++c)
                    s += wylds[r][c] * ylds[bb][c];
                g[q] = s;
            }
            float ig = sigf(g[0]), fg = sigf(g[1]);
            float gv = tanhfast(g[2]), og = sigf(g[3]);
            cstate = fg * cstate + ig * gv;
            float h = og * tanhfast(cstate);
            hnew[bb][u] = h;
            const ull tagbits = ((ull)(unsigned)(t + 2)) << 32;
            const size_t oidx = (size_t)((t + 1) & 1) * 8192
                              + (size_t)(bg * 4 + bb) * 256 + rg * 16 + u;
            __hip_atomic_store(hbuf + oidx, tagbits | (ull)__float_as_uint(h),
                               __ATOMIC_RELAXED, __HIP_MEMORY_SCOPE_AGENT);
            float lp = 0.f;
#pragma unroll
            for (int u2 = 0; u2 < 16; ++u2)
                lp += linl[u][u2] * hnew[bb][u2];
            __hip_atomic_store(lbuf + oidx, tagbits | (ull)__float_as_uint(lp),
                               __ATOMIC_RELAXED, __HIP_MEMORY_SCOPE_AGENT);
        }
    }
}

// ---------------------------------------------------------------------------
extern "C" void kernel_launch(void* const* d_in, const int* in_sizes, int n_in,
                              void* d_out, int out_size, void* d_ws, size_t ws_size,
                              hipStream_t stream)
{
    const float* x     = (const float*)d_in[0];
    const int*   mask  = (const int*)d_in[1];
    const float* Wih_f = (const float*)d_in[2];
    const float* Whh_f = (const float*)d_in[3];
    const float* bih_f = (const float*)d_in[4];
    const float* bhh_f = (const float*)d_in[5];
    const float* Wih_r = (const float*)d_in[6];
    const float* Whh_r = (const float*)d_in[7];
    const float* bih_r = (const float*)d_in[8];
    const float* bhh_r = (const float*)d_in[9];
    const float* fc1_w = (const float*)d_in[10];
    const float* fc2_w = (const float*)d_in[11];
    const float* fc3_w = (const float*)d_in[12];
    const float* fc3_b = (const float*)d_in[13];
    const float* Wih_d = (const float*)d_in[14];
    const float* Whh_d = (const float*)d_in[15];
    const float* bih_d = (const float*)d_in[16];
    const float* bhh_d = (const float*)d_in[17];
    const float* lin_w = (const float*)d_in[18];
    const float* lin_b = (const float*)d_in[19];

    float* ws = (float*)d_ws;
    float* Gf   = ws;
    float* Gr   = ws + 8388608;
    float* hs   = ws + 16777216;
    float* wat  = ws + 25165824;
    float* qp   = ws + 33554432;
    float* kp   = ws + 33718272;
    float* Gd   = ws;
    float* yenc = wat;
    ull* hbuf = (ull*)(wat + 4194304);
    ull* lbuf = hbuf + 16384;

    float* outp = (float*)d_out;
    const int M = NB * TSEQ;       // 16384
    dim3 blk(256);

    // 1-2. encoder input projections (split-bf16 MFMA, 128x128 tiles)
    gemm_mfma<1><<<dim3(M / 128, 4), blk, 0, stream>>>(x, DB, Wih_f, DB, bih_f, bhh_f, Gf, 512, DB);
    gemm_mfma<2><<<dim3(M / 128, 4), blk, 0, stream>>>(x, DB, Wih_r, DB, bih_r, bhh_r, Gr, 512, DB);
    // 3. bidirectional recurrence
    enc_scan<<<dim3(64), dim3(512), 0, stream>>>(Gf, Gr, Whh_f, Whh_r, hs);
    // 4-5. q/k projections (tiny N, f32 64x64)
    gemm_nt<0><<<dim3(M / 64, 1), blk, 0, stream>>>(hs, 512, fc1_w, 512, nullptr, nullptr, qp, 10, 10, 256);
    gemm_nt<0><<<dim3(M / 64, 1), blk, 0, stream>>>(hs, 512, fc1_w + 256, 512, nullptr, nullptr, kp, 10, 10, 256);
    // 6. attention scores + softmax
    attn_w<<<dim3(M), blk, 0, stream>>>(qp, kp, mask, fc2_w, wat);
    // 7. ctx = w @ hs (f32 NN)
    bgemm_nn<<<dim3(8, 4, NB), blk, 0, stream>>>(wat, hs);
    // 8. y_enc (split-bf16 MFMA)
    gemm_mfma<0><<<dim3(M / 128, 2), blk, 0, stream>>>(hs, 512, fc3_w, 512, fc3_b, nullptr, yenc, 256, 512);
    // 8.5 decoder comm init
    dec_init4<<<dim3(16), blk, 0, stream>>>(hs, hbuf, lbuf);
    // 9. decoder input projection (split-bf16 MFMA)
    gemm_mfma<1><<<dim3(M / 128, 8), blk, 0, stream>>>(yenc, 256, Wih_d, 272, bih_d, bhh_d, Gd, 1024, 256);
    // 10. decoder recurrence (unchanged)
    dec_scan8<<<dim3(128), blk, 0, stream>>>(Gd, Whh_d, Wih_d, lin_w, lin_b, hbuf, lbuf, outp);
}

// Round 12
// 2761.123 us; speedup vs baseline: 1.3490x; 1.1157x over previous
//
#include <hip/hip_runtime.h>

// Problem constants
#define TSEQ 512
#define NB   32     // batch
#define DB   768    // d_bert
#define H2E  128    // encoder hidden per dir
#define DL   256    // d_lstm
#define NC   16     // n_class

typedef unsigned long long ull;
typedef float f32x4 __attribute__((ext_vector_type(4)));
typedef short bf16x8 __attribute__((ext_vector_type(8)));
typedef unsigned short u16x8 __attribute__((ext_vector_type(8)));

__device__ __forceinline__ float sigf(float x) { return 1.0f / (1.0f + __expf(-x)); }
__device__ __forceinline__ float tanhfast(float x) { return 1.0f - 2.0f / (1.0f + __expf(2.0f * x)); }

// split f32 -> hi bf16 (RNE) + lo bf16 (RNE of residual)
__device__ __forceinline__ void cvt_split(float a, unsigned short& hi, unsigned short& lo) {
    unsigned u = __float_as_uint(a);
    unsigned h = (u + 0x7FFFu + ((u >> 16) & 1u)) >> 16;
    float hf = __uint_as_float(h << 16);
    float d = a - hf;
    unsigned ud = __float_as_uint(d);
    unsigned l = (ud + 0x7FFFu + ((ud >> 16) & 1u)) >> 16;
    hi = (unsigned short)h;
    lo = (unsigned short)l;
}

// ---------------------------------------------------------------------------
// Split-bf16 MFMA GEMM (unchanged from round 11, validated).
// ---------------------------------------------------------------------------
#define LDST 40
template <int MODE>
__global__ __launch_bounds__(256) void gemm_mfma(
    const float* __restrict__ A, int lda,
    const float* __restrict__ W, int ldw,
    const float* __restrict__ b1, const float* __restrict__ b2,
    float* __restrict__ C, int ldc, int K)
{
    __shared__ unsigned short Ah[128][LDST];
    __shared__ unsigned short Al[128][LDST];
    __shared__ unsigned short Wh[128][LDST];
    __shared__ unsigned short Wl[128][LDST];

    const int tid = threadIdx.x;
    const int m0 = blockIdx.x * 128;
    const int n0 = blockIdx.y * 128;
    const int wave = tid >> 6, lane = tid & 63;
    const int wr = wave >> 1, wc = wave & 1;
    const int fr = lane & 15;
    const int fq = lane >> 4;
    const int srow = tid >> 1, skoff = (tid & 1) * 16;

    f32x4 acc[4][4] = {};

    for (int k0 = 0; k0 < K; k0 += 32) {
        __syncthreads();
        {
            const float* src = A + (size_t)(m0 + srow) * lda + k0 + skoff;
            u16x8 vh0, vh1, vl0, vl1;
#pragma unroll
            for (int e = 0; e < 8; ++e) {
                unsigned short h, l;
                cvt_split(src[e], h, l);
                vh0[e] = h; vl0[e] = l;
                cvt_split(src[e + 8], h, l);
                vh1[e] = h; vl1[e] = l;
            }
            *(u16x8*)&Ah[srow][skoff]     = vh0;
            *(u16x8*)&Ah[srow][skoff + 8] = vh1;
            *(u16x8*)&Al[srow][skoff]     = vl0;
            *(u16x8*)&Al[srow][skoff + 8] = vl1;
        }
        {
            const float* src = W + (size_t)(n0 + srow) * ldw + k0 + skoff;
            u16x8 vh0, vh1, vl0, vl1;
#pragma unroll
            for (int e = 0; e < 8; ++e) {
                unsigned short h, l;
                cvt_split(src[e], h, l);
                vh0[e] = h; vl0[e] = l;
                cvt_split(src[e + 8], h, l);
                vh1[e] = h; vl1[e] = l;
            }
            *(u16x8*)&Wh[srow][skoff]     = vh0;
            *(u16x8*)&Wh[srow][skoff + 8] = vh1;
            *(u16x8*)&Wl[srow][skoff]     = vl0;
            *(u16x8*)&Wl[srow][skoff + 8] = vl1;
        }
        __syncthreads();

        bf16x8 ah[4], al[4], bh[4], bl[4];
#pragma unroll
        for (int i = 0; i < 4; ++i) {
            const int r = wr * 64 + i * 16 + fr;
            ah[i] = *(const bf16x8*)&Ah[r][fq * 8];
            al[i] = *(const bf16x8*)&Al[r][fq * 8];
        }
#pragma unroll
        for (int j = 0; j < 4; ++j) {
            const int r = wc * 64 + j * 16 + fr;
            bh[j] = *(const bf16x8*)&Wh[r][fq * 8];
            bl[j] = *(const bf16x8*)&Wl[r][fq * 8];
        }
#pragma unroll
        for (int i = 0; i < 4; ++i)
#pragma unroll
            for (int j = 0; j < 4; ++j) {
                acc[i][j] = __builtin_amdgcn_mfma_f32_16x16x32_bf16(ah[i], bh[j], acc[i][j], 0, 0, 0);
                acc[i][j] = __builtin_amdgcn_mfma_f32_16x16x32_bf16(ah[i], bl[j], acc[i][j], 0, 0, 0);
                acc[i][j] = __builtin_amdgcn_mfma_f32_16x16x32_bf16(al[i], bh[j], acc[i][j], 0, 0, 0);
            }
    }

#pragma unroll
    for (int i = 0; i < 4; ++i) {
#pragma unroll
        for (int r = 0; r < 4; ++r) {
            int gm = m0 + wr * 64 + i * 16 + fq * 4 + r;
            int orow;
            if (MODE == 0) orow = gm;
            else {
                int bb = gm >> 9;
                int tt = gm & (TSEQ - 1);
                orow = (MODE == 1 ? tt : (TSEQ - 1 - tt)) * NB + bb;
            }
            float* crow = C + (size_t)orow * ldc;
#pragma unroll
            for (int j = 0; j < 4; ++j) {
                int gn = n0 + wc * 64 + j * 16 + fr;
                float bias = (b1 ? b1[gn] : 0.f) + (b2 ? b2[gn] : 0.f);
                crow[gn] = acc[i][j][r] + bias;
            }
        }
    }
}

// ---------------------------------------------------------------------------
// f32 GEMM, 64x64 tile (tiny-N q/k projections only).
// ---------------------------------------------------------------------------
template <int MODE>
__global__ __launch_bounds__(256) void gemm_nt(
    const float* __restrict__ A, int lda,
    const float* __restrict__ W, int ldw,
    const float* __restrict__ b1, const float* __restrict__ b2,
    float* __restrict__ C, int ldc, int N, int K)
{
    __shared__ float As[16][68];
    __shared__ float Ws[16][68];
    const int tid = threadIdx.x;
    const int m0 = blockIdx.x * 64;
    const int n0 = blockIdx.y * 64;
    const int tx = tid & 15, ty = tid >> 4;
    const int lrow = tid >> 2;
    const int lk = (tid & 3) * 4;
    float acc[4][4] = {};

    for (int k0 = 0; k0 < K; k0 += 16) {
        float4 av = *(const float4*)(A + (size_t)(m0 + lrow) * lda + k0 + lk);
        float4 wv = make_float4(0.f, 0.f, 0.f, 0.f);
        if (n0 + lrow < N)
            wv = *(const float4*)(W + (size_t)(n0 + lrow) * ldw + k0 + lk);
        As[lk + 0][lrow] = av.x; As[lk + 1][lrow] = av.y;
        As[lk + 2][lrow] = av.z; As[lk + 3][lrow] = av.w;
        Ws[lk + 0][lrow] = wv.x; Ws[lk + 1][lrow] = wv.y;
        Ws[lk + 2][lrow] = wv.z; Ws[lk + 3][lrow] = wv.w;
        __syncthreads();
#pragma unroll
        for (int kk = 0; kk < 16; ++kk) {
            float a0 = As[kk][ty * 4 + 0], a1 = As[kk][ty * 4 + 1];
            float a2 = As[kk][ty * 4 + 2], a3 = As[kk][ty * 4 + 3];
            float w0 = Ws[kk][tx * 4 + 0], w1 = Ws[kk][tx * 4 + 1];
            float w2 = Ws[kk][tx * 4 + 2], w3 = Ws[kk][tx * 4 + 3];
            acc[0][0] += a0 * w0; acc[0][1] += a0 * w1; acc[0][2] += a0 * w2; acc[0][3] += a0 * w3;
            acc[1][0] += a1 * w0; acc[1][1] += a1 * w1; acc[1][2] += a1 * w2; acc[1][3] += a1 * w3;
            acc[2][0] += a2 * w0; acc[2][1] += a2 * w1; acc[2][2] += a2 * w2; acc[2][3] += a2 * w3;
            acc[3][0] += a3 * w0; acc[3][1] += a3 * w1; acc[3][2] += a3 * w2; acc[3][3] += a3 * w3;
        }
        __syncthreads();
    }

#pragma unroll
    for (int i = 0; i < 4; ++i) {
        int gm = m0 + ty * 4 + i;
        int orow;
        if (MODE == 0) orow = gm;
        else {
            int bb = gm >> 9;
            int tt = gm & (TSEQ - 1);
            orow = (MODE == 1 ? tt : (TSEQ - 1 - tt)) * NB + bb;
        }
#pragma unroll
        for (int j = 0; j < 4; ++j) {
            int gn = n0 + tx * 4 + j;
            if (gn < N) {
                float bias = (b1 ? b1[gn] : 0.f) + (b2 ? b2[gn] : 0.f);
                C[(size_t)orow * ldc + gn] = acc[i][j] + bias;
            }
        }
    }
}

// ---------------------------------------------------------------------------
// Encoder LSTM scan (unchanged).
// ---------------------------------------------------------------------------
__global__ __launch_bounds__(512) void enc_scan(
    const float* __restrict__ Gf, const float* __restrict__ Gr,
    const float* __restrict__ Whh_f, const float* __restrict__ Whh_r,
    float* __restrict__ hs_ctx)
{
    const int dir = blockIdx.x & 1;
    const int b = blockIdx.x >> 1;
    const float* __restrict__ G = dir ? Gr : Gf;
    const float* __restrict__ Whh = dir ? Whh_r : Whh_f;
    const int j = threadIdx.x;

    __shared__ float4 h4[H2E / 4];
    __shared__ float gates[4 * H2E];
    float* h_s = (float*)h4;

    float4 w[32];
#pragma unroll
    for (int k = 0; k < 32; ++k)
        w[k] = *(const float4*)(Whh + (size_t)j * H2E + k * 4);

    float c = 0.f;
    if (j < H2E) h_s[j] = 0.f;
    __syncthreads();

    for (int t = 0; t < TSEQ; ++t) {
        const float* grow = G + ((size_t)t * NB + b) * 512;
        float acc = grow[j];
#pragma unroll
        for (int k = 0; k < 32; ++k) {
            float4 hv = h4[k];
            acc += w[k].x * hv.x + w[k].y * hv.y + w[k].z * hv.z + w[k].w * hv.w;
        }
        gates[j] = acc;
        __syncthreads();
        if (j < H2E) {
            float ig = sigf(gates[j]);
            float fg = sigf(gates[j + H2E]);
            float gg = tanhfast(gates[j + 2 * H2E]);
            float og = sigf(gates[j + 3 * H2E]);
            c = fg * c + ig * gg;
            float h = og * tanhfast(c);
            h_s[j] = h;
            int tout = dir ? (TSEQ - 1 - t) : t;
            hs_ctx[((size_t)b * TSEQ + tout) * 512 + dir * H2E + j] = h;
        }
        __syncthreads();
    }
}

// ---------------------------------------------------------------------------
// Fused additive-attention scores + softmax (unchanged).
// ---------------------------------------------------------------------------
__global__ __launch_bounds__(256) void attn_w(
    const float* __restrict__ qp, const float* __restrict__ kp,
    const int* __restrict__ mask, const float* __restrict__ fc2,
    float* __restrict__ wout)
{
    const int bi = blockIdx.x;
    const int b = bi >> 9;
    const int tid = threadIdx.x;
    __shared__ float kps[TSEQ * 11];
    __shared__ float red[8];

    const float* kpb = kp + (size_t)b * TSEQ * 10;
    for (int idx = tid; idx < TSEQ * 10; idx += 256) {
        int j = idx / 10, xx = idx - j * 10;
        kps[j * 11 + xx] = kpb[idx];
    }
    float q[10], vv[10];
#pragma unroll
    for (int xx = 0; xx < 10; ++xx) {
        q[xx] = qp[(size_t)bi * 10 + xx];
        vv[xx] = fc2[xx];
    }
    __syncthreads();

    float a[2];
#pragma unroll
    for (int jj = 0; jj < 2; ++jj) {
        int j = tid + jj * 256;
        float s = 0.f;
#pragma unroll
        for (int xx = 0; xx < 10; ++xx)
            s += vv[xx] * tanhfast(q[xx] + kps[j * 11 + xx]);
        if (mask[(size_t)b * TSEQ + j] == 0) s = -1e30f;
        a[jj] = s;
    }

    float m = fmaxf(a[0], a[1]);
#pragma unroll
    for (int o = 32; o >= 1; o >>= 1) m = fmaxf(m, __shfl_xor(m, o));
    if ((tid & 63) == 0) red[tid >> 6] = m;
    __syncthreads();
    m = fmaxf(fmaxf(red[0], red[1]), fmaxf(red[2], red[3]));

    float e0 = __expf(a[0] - m), e1 = __expf(a[1] - m);
    float s = e0 + e1;
#pragma unroll
    for (int o = 32; o >= 1; o >>= 1) s += __shfl_xor(s, o);
    if ((tid & 63) == 0) red[4 + (tid >> 6)] = s;
    __syncthreads();
    s = (red[4] + red[5]) + (red[6] + red[7]);
    float inv = 1.0f / s;
    wout[(size_t)bi * TSEQ + tid] = e0 * inv;
    wout[(size_t)bi * TSEQ + tid + 256] = e1 * inv;
}

// ---------------------------------------------------------------------------
// Batched NN GEMM: ctx = w @ hs (unchanged).
// ---------------------------------------------------------------------------
__global__ __launch_bounds__(256) void bgemm_nn(
    const float* __restrict__ Wmat,
    float* __restrict__ hs_ctx)
{
    __shared__ float As[16][68];
    __shared__ float Bs[16][68];
    const int tid = threadIdx.x;
    const int b = blockIdx.z;
    const int i0 = blockIdx.x * 64;
    const int d0 = blockIdx.y * 64;
    const int tx = tid & 15, ty = tid >> 4;
    float acc[4][4] = {};
    const float* Ab = Wmat + (size_t)b * TSEQ * TSEQ;
    const float* Bb = hs_ctx + (size_t)b * TSEQ * 512;

    for (int k0 = 0; k0 < TSEQ; k0 += 16) {
        {
            int r = tid >> 2, kq = (tid & 3) * 4;
            float4 v = *(const float4*)(Ab + (size_t)(i0 + r) * TSEQ + k0 + kq);
            As[kq + 0][r] = v.x; As[kq + 1][r] = v.y; As[kq + 2][r] = v.z; As[kq + 3][r] = v.w;
        }
        {
            int kk = tid >> 4, dq = (tid & 15) * 4;
            float4 v = *(const float4*)(Bb + (size_t)(k0 + kk) * 512 + d0 + dq);
            *(float4*)&Bs[kk][dq] = v;
        }
        __syncthreads();
#pragma unroll
        for (int kk = 0; kk < 16; ++kk) {
            float a0 = As[kk][ty * 4 + 0], a1 = As[kk][ty * 4 + 1];
            float a2 = As[kk][ty * 4 + 2], a3 = As[kk][ty * 4 + 3];
            float b0 = Bs[kk][tx * 4 + 0], b1 = Bs[kk][tx * 4 + 1];
            float b2 = Bs[kk][tx * 4 + 2], b3 = Bs[kk][tx * 4 + 3];
            acc[0][0] += a0 * b0; acc[0][1] += a0 * b1; acc[0][2] += a0 * b2; acc[0][3] += a0 * b3;
            acc[1][0] += a1 * b0; acc[1][1] += a1 * b1; acc[1][2] += a1 * b2; acc[1][3] += a1 * b3;
            acc[2][0] += a2 * b0; acc[2][1] += a2 * b1; acc[2][2] += a2 * b2; acc[2][3] += a2 * b3;
            acc[3][0] += a3 * b0; acc[3][1] += a3 * b1; acc[3][2] += a3 * b2; acc[3][3] += a3 * b3;
        }
        __syncthreads();
    }
#pragma unroll
    for (int i = 0; i < 4; ++i)
#pragma unroll
        for (int j = 0; j < 4; ++j)
            hs_ctx[((size_t)b * TSEQ + i0 + ty * 4 + i) * 512 + 256 + d0 + tx * 4 + j] = acc[i][j];
}

// ---------------------------------------------------------------------------
// Decoder init (unchanged): clear all tags, seed h(-1) tag=1 parity 0.
// ---------------------------------------------------------------------------
__global__ __launch_bounds__(256) void dec_init4(
    const float* __restrict__ hs_ctx, ull* hbuf, ull* lbuf)
{
    const int gid = blockIdx.x * 256 + threadIdx.x;
    for (int idx = gid; idx < 32768; idx += 16 * 256) {
        ull v = 0ull;
        if (idx < 8192) {
            int b = idx >> 8, u = idx & 255;
            float hv = hs_ctx[((size_t)b * TSEQ + (TSEQ - 1)) * 512 + u];
            v = (1ull << 32) | (ull)__float_as_uint(hv);
        }
        ull* dst = (idx < 16384) ? (hbuf + idx) : (lbuf + (idx - 16384));
        __hip_atomic_store(dst, v, __ATOMIC_RELAXED, __HIP_MEMORY_SCOPE_AGENT);
    }
}

// ---------------------------------------------------------------------------
// Decoder scan v10: MFMA gate dot (split-bf16), scan8's validated tag sync.
// 128 blocks = 16 rg x 8 bg. Per block the dot is M=4(batch) x N=64(rows) x
// K=256. Wave w owns N-tile rows [w*16,w*16+16): gate type w, units 0..15.
// Weights staged ONCE to LDS as hi/lo bf16 [64][264]; h converted per step
// (cvt_split x4/thread). Per K-step each lane reads 4 b128 frags, issues
// 3 MFMAs (hh+hl+lh). A-frag batch row clamped (lane&3): D rows 4-15 are
// duplicates, ignored. D: lanes 0-15, reg=batch, col=unit -> gpart[4][4][18].
// Finalize (wave0, 64 thr): gates = gpart + Gd + Wy*y, LSTM update, publish.
// ---------------------------------------------------------------------------
__global__ __launch_bounds__(256) void dec_scan9(
    const float* __restrict__ Gd,     // (T, NB, 1024), biases folded
    const float* __restrict__ Whh,    // (1024, 256)
    const float* __restrict__ Wih,    // (1024, 272); cols 256:272 multiply y
    const float* __restrict__ lin_w,  // (16, 256)
    const float* __restrict__ lin_b,  // (16,)
    ull* hbuf,                        // (2, NB, 256) tagged h
    ull* lbuf,                        // (2, NB, 256) tagged logit partials
    float* __restrict__ out)          // (NB, T, NC)
{
    const int tid = threadIdx.x;
    const int rg  = blockIdx.x & 15;
    const int bg  = blockIdx.x >> 4;
    const int wave = tid >> 6;
    const int lane = tid & 63;
    const int fr = lane & 15;         // fragment row/col
    const int fq = lane >> 4;         // k-octet
    const bool isw1 = (wave == 1);
    const int ybb = (tid >> 4) & 3;
    const int ycls = tid & 15;

    __shared__ unsigned short wbh[64][264];  // Whh slice hi (bf16)
    __shared__ unsigned short wbl[64][264];  // Whh slice lo
    __shared__ unsigned short hbh[4][264];   // h(t-1) hi
    __shared__ unsigned short hbl[4][264];   // h(t-1) lo
    __shared__ float gpart[4][4][18];        // [gate q][bb][u]
    __shared__ float ylds[4][17];
    __shared__ float hnew[4][17];
    __shared__ float linl[16][17];
    __shared__ float wylds[64][17];

    // ---- one-time staging: weights -> hi/lo bf16 ----
    for (int idx = tid; idx < 64 * 256; idx += 256) {
        int row = idx >> 8, c = idx & 255;
        int j = ((row >> 4) << 8) + rg * 16 + (row & 15);
        unsigned short h, l;
        cvt_split(Whh[(size_t)j * 256 + c], h, l);
        wbh[row][c] = h;
        wbl[row][c] = l;
    }
    {
        int r = tid >> 2, c0 = (tid & 3) * 4;
        int j = ((r >> 4) << 8) + rg * 16 + (r & 15);
        const float* src = Wih + (size_t)j * 272 + 256 + c0;
        wylds[r][c0 + 0] = src[0]; wylds[r][c0 + 1] = src[1];
        wylds[r][c0 + 2] = src[2]; wylds[r][c0 + 3] = src[3];
    }
    linl[tid >> 4][tid & 15] = lin_w[(tid >> 4) * 256 + rg * 16 + (tid & 15)];
    const float lb = lin_b[ycls];
    float cstate = 0.f;
    __syncthreads();

    for (int t = 0; t <= TSEQ; ++t) {
        const unsigned want = (unsigned)(t + 1);
        const ull* hsrc = hbuf + (size_t)(t & 1) * 8192 + (size_t)bg * 1024;
        const ull* lsrc = lbuf + (size_t)(t & 1) * 8192 + (size_t)bg * 1024;

        // Gd prefetch for finalize threads: rows q*256+rg*16+u, batch bg*4+bb
        float gdv[4] = {0.f, 0.f, 0.f, 0.f};
        if (tid < 64 && t < TSEQ) {
            const float* gb = Gd + ((size_t)t * NB + bg * 4 + ybb) * 1024 + rg * 16 + ycls;
#pragma unroll
            for (int q = 0; q < 4; ++q) gdv[q] = gb[q * 256];
        }
        __builtin_amdgcn_sched_barrier(0);

        // ---- wave1: y-path (poll tagged logit partials, softmax, out) ----
        if (isw1) {
            float yv = 0.f;
            if (t > 0) {
                float lsum;
                for (;;) {
                    lsum = lb;
                    bool ok = true;
#pragma unroll
                    for (int r = 0; r < 16; ++r) {
                        ull lv = __hip_atomic_load(lsrc + ybb * 256 + r * 16 + ycls,
                                                   __ATOMIC_RELAXED, __HIP_MEMORY_SCOPE_AGENT);
                        ok &= ((unsigned)(lv >> 32) == want);
                        lsum += __uint_as_float((unsigned)lv);
                    }
                    if (ok) break;
                    __builtin_amdgcn_s_sleep(1);
                }
                float m = lsum;
#pragma unroll
                for (int o = 1; o < 16; o <<= 1) m = fmaxf(m, __shfl_xor(m, o, 16));
                float e = __expf(lsum - m);
                float ss = e;
#pragma unroll
                for (int o = 1; o < 16; o <<= 1) ss += __shfl_xor(ss, o, 16);
                yv = e / ss;
                if (rg == 0)
                    out[(((size_t)(bg * 4 + ybb)) * TSEQ + (t - 1)) * NC + ycls] = yv;
            }
            ylds[ybb][ycls] = yv;
        }

        // ---- all threads: verify own 4 tagged h-words; convert + stage ----
        {
            ull h0, h1, h2, h3;
            for (;;) {
                h0 = __hip_atomic_load(hsrc + tid,       __ATOMIC_RELAXED, __HIP_MEMORY_SCOPE_AGENT);
                h1 = __hip_atomic_load(hsrc + tid + 256, __ATOMIC_RELAXED, __HIP_MEMORY_SCOPE_AGENT);
                h2 = __hip_atomic_load(hsrc + tid + 512, __ATOMIC_RELAXED, __HIP_MEMORY_SCOPE_AGENT);
                h3 = __hip_atomic_load(hsrc + tid + 768, __ATOMIC_RELAXED, __HIP_MEMORY_SCOPE_AGENT);
                if (((unsigned)(h0 >> 32) == want) && ((unsigned)(h1 >> 32) == want) &&
                    ((unsigned)(h2 >> 32) == want) && ((unsigned)(h3 >> 32) == want))
                    break;
                __builtin_amdgcn_s_sleep(1);
            }
            unsigned short hh, hl;
            cvt_split(__uint_as_float((unsigned)h0), hh, hl);
            hbh[0][tid] = hh; hbl[0][tid] = hl;
            cvt_split(__uint_as_float((unsigned)h1), hh, hl);
            hbh[1][tid] = hh; hbl[1][tid] = hl;
            cvt_split(__uint_as_float((unsigned)h2), hh, hl);
            hbh[2][tid] = hh; hbl[2][tid] = hl;
            cvt_split(__uint_as_float((unsigned)h3), hh, hl);
            hbh[3][tid] = hh; hbl[3][tid] = hl;
        }
        __syncthreads();   // hbh/hbl + ylds ready

        if (t == TSEQ) break;

        // ---- MFMA gate dot: D[batch][row] over K=256 (8 K-steps) ----
        {
            f32x4 acc = {};
            const int abrow = lane & 3;          // clamped batch row
            const int wrow = wave * 16 + fr;     // weight row for B-frag
#pragma unroll
            for (int ks = 0; ks < 8; ++ks) {
                const int kc = ks * 32 + fq * 8;
                bf16x8 ahi = *(const bf16x8*)&hbh[abrow][kc];
                bf16x8 alo = *(const bf16x8*)&hbl[abrow][kc];
                bf16x8 bhi = *(const bf16x8*)&wbh[wrow][kc];
                bf16x8 blo = *(const bf16x8*)&wbl[wrow][kc];
                acc = __builtin_amdgcn_mfma_f32_16x16x32_bf16(ahi, bhi, acc, 0, 0, 0);
                acc = __builtin_amdgcn_mfma_f32_16x16x32_bf16(ahi, blo, acc, 0, 0, 0);
                acc = __builtin_amdgcn_mfma_f32_16x16x32_bf16(alo, bhi, acc, 0, 0, 0);
            }
            // D: col=lane&15 (unit), row=fq*4+reg (batch for fq==0)
            if (fq == 0) {
#pragma unroll
                for (int reg = 0; reg < 4; ++reg)
                    gpart[wave][reg][fr] = acc[reg];
            }
        }
        __syncthreads();   // gpart ready

        // ---- finalize (wave0): gates + Gd + y-term, LSTM update, publish ----
        if (tid < 64) {
            const int bb = ybb, u = ycls;
            float g[4];
#pragma unroll
            for (int q = 0; q < 4; ++q) {
                float s = gpart[q][bb][u] + gdv[q];
                const int r = q * 16 + u;
#pragma unroll
                for (int c = 0; c < 16; ++c)
                    s += wylds[r][c] * ylds[bb][c];
                g[q] = s;
            }
            float ig = sigf(g[0]), fg = sigf(g[1]);
            float gv = tanhfast(g[2]), og = sigf(g[3]);
            cstate = fg * cstate + ig * gv;
            float h = og * tanhfast(cstate);
            hnew[bb][u] = h;
            const ull tagbits = ((ull)(unsigned)(t + 2)) << 32;
            const size_t oidx = (size_t)((t + 1) & 1) * 8192
                              + (size_t)(bg * 4 + bb) * 256 + rg * 16 + u;
            __hip_atomic_store(hbuf + oidx, tagbits | (ull)__float_as_uint(h),
                               __ATOMIC_RELAXED, __HIP_MEMORY_SCOPE_AGENT);
            float lp = 0.f;
#pragma unroll
            for (int u2 = 0; u2 < 16; ++u2)
                lp += linl[u][u2] * hnew[bb][u2];
            __hip_atomic_store(lbuf + oidx, tagbits | (ull)__float_as_uint(lp),
                               __ATOMIC_RELAXED, __HIP_MEMORY_SCOPE_AGENT);
        }
        // no trailing barrier: next-step poll self-gates on our publish
    }
}

// ---------------------------------------------------------------------------
extern "C" void kernel_launch(void* const* d_in, const int* in_sizes, int n_in,
                              void* d_out, int out_size, void* d_ws, size_t ws_size,
                              hipStream_t stream)
{
    const float* x     = (const float*)d_in[0];
    const int*   mask  = (const int*)d_in[1];
    const float* Wih_f = (const float*)d_in[2];
    const float* Whh_f = (const float*)d_in[3];
    const float* bih_f = (const float*)d_in[4];
    const float* bhh_f = (const float*)d_in[5];
    const float* Wih_r = (const float*)d_in[6];
    const float* Whh_r = (const float*)d_in[7];
    const float* bih_r = (const float*)d_in[8];
    const float* bhh_r = (const float*)d_in[9];
    const float* fc1_w = (const float*)d_in[10];
    const float* fc2_w = (const float*)d_in[11];
    const float* fc3_w = (const float*)d_in[12];
    const float* fc3_b = (const float*)d_in[13];
    const float* Wih_d = (const float*)d_in[14];
    const float* Whh_d = (const float*)d_in[15];
    const float* bih_d = (const float*)d_in[16];
    const float* bhh_d = (const float*)d_in[17];
    const float* lin_w = (const float*)d_in[18];
    const float* lin_b = (const float*)d_in[19];

    float* ws = (float*)d_ws;
    float* Gf   = ws;
    float* Gr   = ws + 8388608;
    float* hs   = ws + 16777216;
    float* wat  = ws + 25165824;
    float* qp   = ws + 33554432;
    float* kp   = ws + 33718272;
    float* Gd   = ws;
    float* yenc = wat;
    ull* hbuf = (ull*)(wat + 4194304);
    ull* lbuf = hbuf + 16384;

    float* outp = (float*)d_out;
    const int M = NB * TSEQ;       // 16384
    dim3 blk(256);

    // 1-2. encoder input projections (split-bf16 MFMA, 128x128 tiles)
    gemm_mfma<1><<<dim3(M / 128, 4), blk, 0, stream>>>(x, DB, Wih_f, DB, bih_f, bhh_f, Gf, 512, DB);
    gemm_mfma<2><<<dim3(M / 128, 4), blk, 0, stream>>>(x, DB, Wih_r, DB, bih_r, bhh_r, Gr, 512, DB);
    // 3. bidirectional recurrence
    enc_scan<<<dim3(64), dim3(512), 0, stream>>>(Gf, Gr, Whh_f, Whh_r, hs);
    // 4-5. q/k projections (tiny N, f32 64x64)
    gemm_nt<0><<<dim3(M / 64, 1), blk, 0, stream>>>(hs, 512, fc1_w, 512, nullptr, nullptr, qp, 10, 10, 256);
    gemm_nt<0><<<dim3(M / 64, 1), blk, 0, stream>>>(hs, 512, fc1_w + 256, 512, nullptr, nullptr, kp, 10, 10, 256);
    // 6. attention scores + softmax
    attn_w<<<dim3(M), blk, 0, stream>>>(qp, kp, mask, fc2_w, wat);
    // 7. ctx = w @ hs (f32 NN)
    bgemm_nn<<<dim3(8, 4, NB), blk, 0, stream>>>(wat, hs);
    // 8. y_enc (split-bf16 MFMA)
    gemm_mfma<0><<<dim3(M / 128, 2), blk, 0, stream>>>(hs, 512, fc3_w, 512, fc3_b, nullptr, yenc, 256, 512);
    // 8.5 decoder comm init
    dec_init4<<<dim3(16), blk, 0, stream>>>(hs, hbuf, lbuf);
    // 9. decoder input projection (split-bf16 MFMA)
    gemm_mfma<1><<<dim3(M / 128, 8), blk, 0, stream>>>(yenc, 256, Wih_d, 272, bih_d, bhh_d, Gd, 1024, 256);
    // 10. decoder recurrence (MFMA gate dot + tag sync)
    dec_scan9<<<dim3(128), blk, 0, stream>>>(Gd, Whh_d, Wih_d, lin_w, lin_b, hbuf, lbuf, outp);
}

// Round 13
// 2434.036 us; speedup vs baseline: 1.5303x; 1.1344x over previous
//
#include <hip/hip_runtime.h>

// Problem constants
#define TSEQ 512
#define NB   32     // batch
#define DB   768    // d_bert
#define H2E  128    // encoder hidden per dir
#define DL   256    // d_lstm
#define NC   16     // n_class

typedef unsigned long long ull;
typedef float f32x4 __attribute__((ext_vector_type(4)));
typedef short bf16x8 __attribute__((ext_vector_type(8)));
typedef unsigned short u16x8 __attribute__((ext_vector_type(8)));

__device__ __forceinline__ float sigf(float x) { return 1.0f / (1.0f + __expf(-x)); }
__device__ __forceinline__ float tanhfast(float x) { return 1.0f - 2.0f / (1.0f + __expf(2.0f * x)); }

// split f32 -> hi bf16 (RNE) + lo bf16 (RNE of residual)
__device__ __forceinline__ void cvt_split(float a, unsigned short& hi, unsigned short& lo) {
    unsigned u = __float_as_uint(a);
    unsigned h = (u + 0x7FFFu + ((u >> 16) & 1u)) >> 16;
    float hf = __uint_as_float(h << 16);
    float d = a - hf;
    unsigned ud = __float_as_uint(d);
    unsigned l = (ud + 0x7FFFu + ((ud >> 16) & 1u)) >> 16;
    hi = (unsigned short)h;
    lo = (unsigned short)l;
}

// ---------------------------------------------------------------------------
// Split-bf16 MFMA GEMM (validated round 11).
// ---------------------------------------------------------------------------
#define LDST 40
template <int MODE>
__global__ __launch_bounds__(256) void gemm_mfma(
    const float* __restrict__ A, int lda,
    const float* __restrict__ W, int ldw,
    const float* __restrict__ b1, const float* __restrict__ b2,
    float* __restrict__ C, int ldc, int K)
{
    __shared__ unsigned short Ah[128][LDST];
    __shared__ unsigned short Al[128][LDST];
    __shared__ unsigned short Wh[128][LDST];
    __shared__ unsigned short Wl[128][LDST];

    const int tid = threadIdx.x;
    const int m0 = blockIdx.x * 128;
    const int n0 = blockIdx.y * 128;
    const int wave = tid >> 6, lane = tid & 63;
    const int wr = wave >> 1, wc = wave & 1;
    const int fr = lane & 15;
    const int fq = lane >> 4;
    const int srow = tid >> 1, skoff = (tid & 1) * 16;

    f32x4 acc[4][4] = {};

    for (int k0 = 0; k0 < K; k0 += 32) {
        __syncthreads();
        {
            const float* src = A + (size_t)(m0 + srow) * lda + k0 + skoff;
            u16x8 vh0, vh1, vl0, vl1;
#pragma unroll
            for (int e = 0; e < 8; ++e) {
                unsigned short h, l;
                cvt_split(src[e], h, l);
                vh0[e] = h; vl0[e] = l;
                cvt_split(src[e + 8], h, l);
                vh1[e] = h; vl1[e] = l;
            }
            *(u16x8*)&Ah[srow][skoff]     = vh0;
            *(u16x8*)&Ah[srow][skoff + 8] = vh1;
            *(u16x8*)&Al[srow][skoff]     = vl0;
            *(u16x8*)&Al[srow][skoff + 8] = vl1;
        }
        {
            const float* src = W + (size_t)(n0 + srow) * ldw + k0 + skoff;
            u16x8 vh0, vh1, vl0, vl1;
#pragma unroll
            for (int e = 0; e < 8; ++e) {
                unsigned short h, l;
                cvt_split(src[e], h, l);
                vh0[e] = h; vl0[e] = l;
                cvt_split(src[e + 8], h, l);
                vh1[e] = h; vl1[e] = l;
            }
            *(u16x8*)&Wh[srow][skoff]     = vh0;
            *(u16x8*)&Wh[srow][skoff + 8] = vh1;
            *(u16x8*)&Wl[srow][skoff]     = vl0;
            *(u16x8*)&Wl[srow][skoff + 8] = vl1;
        }
        __syncthreads();

        bf16x8 ah[4], al[4], bh[4], bl[4];
#pragma unroll
        for (int i = 0; i < 4; ++i) {
            const int r = wr * 64 + i * 16 + fr;
            ah[i] = *(const bf16x8*)&Ah[r][fq * 8];
            al[i] = *(const bf16x8*)&Al[r][fq * 8];
        }
#pragma unroll
        for (int j = 0; j < 4; ++j) {
            const int r = wc * 64 + j * 16 + fr;
            bh[j] = *(const bf16x8*)&Wh[r][fq * 8];
            bl[j] = *(const bf16x8*)&Wl[r][fq * 8];
        }
#pragma unroll
        for (int i = 0; i < 4; ++i)
#pragma unroll
            for (int j = 0; j < 4; ++j) {
                acc[i][j] = __builtin_amdgcn_mfma_f32_16x16x32_bf16(ah[i], bh[j], acc[i][j], 0, 0, 0);
                acc[i][j] = __builtin_amdgcn_mfma_f32_16x16x32_bf16(ah[i], bl[j], acc[i][j], 0, 0, 0);
                acc[i][j] = __builtin_amdgcn_mfma_f32_16x16x32_bf16(al[i], bh[j], acc[i][j], 0, 0, 0);
            }
    }

#pragma unroll
    for (int i = 0; i < 4; ++i) {
#pragma unroll
        for (int r = 0; r < 4; ++r) {
            int gm = m0 + wr * 64 + i * 16 + fq * 4 + r;
            int orow;
            if (MODE == 0) orow = gm;
            else {
                int bb = gm >> 9;
                int tt = gm & (TSEQ - 1);
                orow = (MODE == 1 ? tt : (TSEQ - 1 - tt)) * NB + bb;
            }
            float* crow = C + (size_t)orow * ldc;
#pragma unroll
            for (int j = 0; j < 4; ++j) {
                int gn = n0 + wc * 64 + j * 16 + fr;
                float bias = (b1 ? b1[gn] : 0.f) + (b2 ? b2[gn] : 0.f);
                crow[gn] = acc[i][j][r] + bias;
            }
        }
    }
}

// ---------------------------------------------------------------------------
// f32 GEMM, 64x64 tile (tiny-N q/k projections only).
// ---------------------------------------------------------------------------
template <int MODE>
__global__ __launch_bounds__(256) void gemm_nt(
    const float* __restrict__ A, int lda,
    const float* __restrict__ W, int ldw,
    const float* __restrict__ b1, const float* __restrict__ b2,
    float* __restrict__ C, int ldc, int N, int K)
{
    __shared__ float As[16][68];
    __shared__ float Ws[16][68];
    const int tid = threadIdx.x;
    const int m0 = blockIdx.x * 64;
    const int n0 = blockIdx.y * 64;
    const int tx = tid & 15, ty = tid >> 4;
    const int lrow = tid >> 2;
    const int lk = (tid & 3) * 4;
    float acc[4][4] = {};

    for (int k0 = 0; k0 < K; k0 += 16) {
        float4 av = *(const float4*)(A + (size_t)(m0 + lrow) * lda + k0 + lk);
        float4 wv = make_float4(0.f, 0.f, 0.f, 0.f);
        if (n0 + lrow < N)
            wv = *(const float4*)(W + (size_t)(n0 + lrow) * ldw + k0 + lk);
        As[lk + 0][lrow] = av.x; As[lk + 1][lrow] = av.y;
        As[lk + 2][lrow] = av.z; As[lk + 3][lrow] = av.w;
        Ws[lk + 0][lrow] = wv.x; Ws[lk + 1][lrow] = wv.y;
        Ws[lk + 2][lrow] = wv.z; Ws[lk + 3][lrow] = wv.w;
        __syncthreads();
#pragma unroll
        for (int kk = 0; kk < 16; ++kk) {
            float a0 = As[kk][ty * 4 + 0], a1 = As[kk][ty * 4 + 1];
            float a2 = As[kk][ty * 4 + 2], a3 = As[kk][ty * 4 + 3];
            float w0 = Ws[kk][tx * 4 + 0], w1 = Ws[kk][tx * 4 + 1];
            float w2 = Ws[kk][tx * 4 + 2], w3 = Ws[kk][tx * 4 + 3];
            acc[0][0] += a0 * w0; acc[0][1] += a0 * w1; acc[0][2] += a0 * w2; acc[0][3] += a0 * w3;
            acc[1][0] += a1 * w0; acc[1][1] += a1 * w1; acc[1][2] += a1 * w2; acc[1][3] += a1 * w3;
            acc[2][0] += a2 * w0; acc[2][1] += a2 * w1; acc[2][2] += a2 * w2; acc[2][3] += a2 * w3;
            acc[3][0] += a3 * w0; acc[3][1] += a3 * w1; acc[3][2] += a3 * w2; acc[3][3] += a3 * w3;
        }
        __syncthreads();
    }

#pragma unroll
    for (int i = 0; i < 4; ++i) {
        int gm = m0 + ty * 4 + i;
        int orow;
        if (MODE == 0) orow = gm;
        else {
            int bb = gm >> 9;
            int tt = gm & (TSEQ - 1);
            orow = (MODE == 1 ? tt : (TSEQ - 1 - tt)) * NB + bb;
        }
#pragma unroll
        for (int j = 0; j < 4; ++j) {
            int gn = n0 + tx * 4 + j;
            if (gn < N) {
                float bias = (b1 ? b1[gn] : 0.f) + (b2 ? b2[gn] : 0.f);
                C[(size_t)orow * ldc + gn] = acc[i][j] + bias;
            }
        }
    }
}

// ---------------------------------------------------------------------------
// Encoder LSTM scan (unchanged).
// ---------------------------------------------------------------------------
__global__ __launch_bounds__(512) void enc_scan(
    const float* __restrict__ Gf, const float* __restrict__ Gr,
    const float* __restrict__ Whh_f, const float* __restrict__ Whh_r,
    float* __restrict__ hs_ctx)
{
    const int dir = blockIdx.x & 1;
    const int b = blockIdx.x >> 1;
    const float* __restrict__ G = dir ? Gr : Gf;
    const float* __restrict__ Whh = dir ? Whh_r : Whh_f;
    const int j = threadIdx.x;

    __shared__ float4 h4[H2E / 4];
    __shared__ float gates[4 * H2E];
    float* h_s = (float*)h4;

    float4 w[32];
#pragma unroll
    for (int k = 0; k < 32; ++k)
        w[k] = *(const float4*)(Whh + (size_t)j * H2E + k * 4);

    float c = 0.f;
    if (j < H2E) h_s[j] = 0.f;
    __syncthreads();

    for (int t = 0; t < TSEQ; ++t) {
        const float* grow = G + ((size_t)t * NB + b) * 512;
        float acc = grow[j];
#pragma unroll
        for (int k = 0; k < 32; ++k) {
            float4 hv = h4[k];
            acc += w[k].x * hv.x + w[k].y * hv.y + w[k].z * hv.z + w[k].w * hv.w;
        }
        gates[j] = acc;
        __syncthreads();
        if (j < H2E) {
            float ig = sigf(gates[j]);
            float fg = sigf(gates[j + H2E]);
            float gg = tanhfast(gates[j + 2 * H2E]);
            float og = sigf(gates[j + 3 * H2E]);
            c = fg * c + ig * gg;
            float h = og * tanhfast(c);
            h_s[j] = h;
            int tout = dir ? (TSEQ - 1 - t) : t;
            hs_ctx[((size_t)b * TSEQ + tout) * 512 + dir * H2E + j] = h;
        }
        __syncthreads();
    }
}

// ---------------------------------------------------------------------------
// Fused additive-attention scores + softmax (unchanged).
// ---------------------------------------------------------------------------
__global__ __launch_bounds__(256) void attn_w(
    const float* __restrict__ qp, const float* __restrict__ kp,
    const int* __restrict__ mask, const float* __restrict__ fc2,
    float* __restrict__ wout)
{
    const int bi = blockIdx.x;
    const int b = bi >> 9;
    const int tid = threadIdx.x;
    __shared__ float kps[TSEQ * 11];
    __shared__ float red[8];

    const float* kpb = kp + (size_t)b * TSEQ * 10;
    for (int idx = tid; idx < TSEQ * 10; idx += 256) {
        int j = idx / 10, xx = idx - j * 10;
        kps[j * 11 + xx] = kpb[idx];
    }
    float q[10], vv[10];
#pragma unroll
    for (int xx = 0; xx < 10; ++xx) {
        q[xx] = qp[(size_t)bi * 10 + xx];
        vv[xx] = fc2[xx];
    }
    __syncthreads();

    float a[2];
#pragma unroll
    for (int jj = 0; jj < 2; ++jj) {
        int j = tid + jj * 256;
        float s = 0.f;
#pragma unroll
        for (int xx = 0; xx < 10; ++xx)
            s += vv[xx] * tanhfast(q[xx] + kps[j * 11 + xx]);
        if (mask[(size_t)b * TSEQ + j] == 0) s = -1e30f;
        a[jj] = s;
    }

    float m = fmaxf(a[0], a[1]);
#pragma unroll
    for (int o = 32; o >= 1; o >>= 1) m = fmaxf(m, __shfl_xor(m, o));
    if ((tid & 63) == 0) red[tid >> 6] = m;
    __syncthreads();
    m = fmaxf(fmaxf(red[0], red[1]), fmaxf(red[2], red[3]));

    float e0 = __expf(a[0] - m), e1 = __expf(a[1] - m);
    float s = e0 + e1;
#pragma unroll
    for (int o = 32; o >= 1; o >>= 1) s += __shfl_xor(s, o);
    if ((tid & 63) == 0) red[4 + (tid >> 6)] = s;
    __syncthreads();
    s = (red[4] + red[5]) + (red[6] + red[7]);
    float inv = 1.0f / s;
    wout[(size_t)bi * TSEQ + tid] = e0 * inv;
    wout[(size_t)bi * TSEQ + tid + 256] = e1 * inv;
}

// ---------------------------------------------------------------------------
// Batched NN GEMM: ctx = w @ hs (unchanged).
// ---------------------------------------------------------------------------
__global__ __launch_bounds__(256) void bgemm_nn(
    const float* __restrict__ Wmat,
    float* __restrict__ hs_ctx)
{
    __shared__ float As[16][68];
    __shared__ float Bs[16][68];
    const int tid = threadIdx.x;
    const int b = blockIdx.z;
    const int i0 = blockIdx.x * 64;
    const int d0 = blockIdx.y * 64;
    const int tx = tid & 15, ty = tid >> 4;
    float acc[4][4] = {};
    const float* Ab = Wmat + (size_t)b * TSEQ * TSEQ;
    const float* Bb = hs_ctx + (size_t)b * TSEQ * 512;

    for (int k0 = 0; k0 < TSEQ; k0 += 16) {
        {
            int r = tid >> 2, kq = (tid & 3) * 4;
            float4 v = *(const float4*)(Ab + (size_t)(i0 + r) * TSEQ + k0 + kq);
            As[kq + 0][r] = v.x; As[kq + 1][r] = v.y; As[kq + 2][r] = v.z; As[kq + 3][r] = v.w;
        }
        {
            int kk = tid >> 4, dq = (tid & 15) * 4;
            float4 v = *(const float4*)(Bb + (size_t)(k0 + kk) * 512 + d0 + dq);
            *(float4*)&Bs[kk][dq] = v;
        }
        __syncthreads();
#pragma unroll
        for (int kk = 0; kk < 16; ++kk) {
            float a0 = As[kk][ty * 4 + 0], a1 = As[kk][ty * 4 + 1];
            float a2 = As[kk][ty * 4 + 2], a3 = As[kk][ty * 4 + 3];
            float b0 = Bs[kk][tx * 4 + 0], b1 = Bs[kk][tx * 4 + 1];
            float b2 = Bs[kk][tx * 4 + 2], b3 = Bs[kk][tx * 4 + 3];
            acc[0][0] += a0 * b0; acc[0][1] += a0 * b1; acc[0][2] += a0 * b2; acc[0][3] += a0 * b3;
            acc[1][0] += a1 * b0; acc[1][1] += a1 * b1; acc[1][2] += a1 * b2; acc[1][3] += a1 * b3;
            acc[2][0] += a2 * b0; acc[2][1] += a2 * b1; acc[2][2] += a2 * b2; acc[2][3] += a2 * b3;
            acc[3][0] += a3 * b0; acc[3][1] += a3 * b1; acc[3][2] += a3 * b2; acc[3][3] += a3 * b3;
        }
        __syncthreads();
    }
#pragma unroll
    for (int i = 0; i < 4; ++i)
#pragma unroll
        for (int j = 0; j < 4; ++j)
            hs_ctx[((size_t)b * TSEQ + i0 + ty * 4 + i) * 512 + 256 + d0 + tx * 4 + j] = acc[i][j];
}

// ---------------------------------------------------------------------------
// Decoder init: clear hbuf tags (both parities), seed h(-1) tag=1 parity 0.
// ---------------------------------------------------------------------------
__global__ __launch_bounds__(256) void dec_init5(
    const float* __restrict__ hs_ctx, ull* hbuf)
{
    const int gid = blockIdx.x * 256 + threadIdx.x;
    for (int idx = gid; idx < 16384; idx += 16 * 256) {
        ull v = 0ull;
        if (idx < 8192) {
            int b = idx >> 8, u = idx & 255;
            float hv = hs_ctx[((size_t)b * TSEQ + (TSEQ - 1)) * 512 + u];
            v = (1ull << 32) | (ull)__float_as_uint(hv);
        }
        __hip_atomic_store(hbuf + idx, v, __ATOMIC_RELAXED, __HIP_MEMORY_SCOPE_AGENT);
    }
}

// ---------------------------------------------------------------------------
// Decoder scan v11: single-hop sync. 128 blocks (16 rg x 8 bg) x 320 threads
// (5 waves). Per step: threads 0-255 poll h(t-1) (tagged words, own 4) and
// stage as hi/lo bf16. One MFMA dot computes 80 N-rows: waves 0-3 = 64 gate
// rows (this block's rg slice), wave 4 = 16 lin_w rows -> logits(h(t-1)).
// Wave 4 then does the whole tail alone: softmax -> y(t-1) (in-wave shuffle
// broadcast), gates = gpart + Gd + Wy*y, LSTM update, publish h (tag t+2).
// lbuf / logit-partial publishing is GONE -> one L3 hop per step.
// WAR: gpart/hbh(t+1) writes ordered after barrier2/poll-detect as before.
// ---------------------------------------------------------------------------
__global__ __launch_bounds__(320) void dec_scan10(
    const float* __restrict__ Gd,     // (T, NB, 1024), biases folded
    const float* __restrict__ Whh,    // (1024, 256)
    const float* __restrict__ Wih,    // (1024, 272); cols 256:272 multiply y
    const float* __restrict__ lin_w,  // (16, 256)
    const float* __restrict__ lin_b,  // (16,)
    ull* hbuf,                        // (2, NB, 256) tagged h
    float* __restrict__ out)          // (NB, T, NC)
{
    const int tid = threadIdx.x;
    const int rg  = blockIdx.x & 15;
    const int bg  = blockIdx.x >> 4;
    const int wave = tid / 64;
    const int lane = tid & 63;
    const int fr = lane & 15;         // fragment row/col
    const int fq = lane >> 4;         // k-octet
    const bool isw4 = (wave == 4);
    const int ybb = (lane >> 4) & 3;  // finalize (bb,u) for wave4
    const int ycls = lane & 15;

    __shared__ unsigned short wbh[64][264];  // Whh slice hi
    __shared__ unsigned short wbl[64][264];  // Whh slice lo
    __shared__ unsigned short lwh[16][264];  // lin_w hi
    __shared__ unsigned short lwl[16][264];  // lin_w lo
    __shared__ unsigned short hbh[4][264];   // h(t-1) hi
    __shared__ unsigned short hbl[4][264];   // h(t-1) lo
    __shared__ float gpart[4][4][18];        // [gate q][bb][u]
    __shared__ float lgp[4][18];             // logits [bb][cls]
    __shared__ float wylds[64][17];          // y-term weights

    // ---- one-time staging ----
    for (int idx = tid; idx < 64 * 256; idx += 320) {
        int row = idx >> 8, c = idx & 255;
        int j = ((row >> 4) << 8) + rg * 16 + (row & 15);
        unsigned short h, l;
        cvt_split(Whh[(size_t)j * 256 + c], h, l);
        wbh[row][c] = h;
        wbl[row][c] = l;
    }
    for (int idx = tid; idx < 16 * 256; idx += 320) {
        int row = idx >> 8, c = idx & 255;
        unsigned short h, l;
        cvt_split(lin_w[(size_t)row * 256 + c], h, l);
        lwh[row][c] = h;
        lwl[row][c] = l;
    }
    for (int idx = tid; idx < 64 * 16; idx += 320) {
        int r = idx >> 4, c = idx & 15;
        int j = ((r >> 4) << 8) + rg * 16 + (r & 15);
        wylds[r][c] = Wih[(size_t)j * 272 + 256 + c];
    }
    const float lb = lin_b[ycls];
    float cstate = 0.f;
    __syncthreads();

    for (int t = 0; t <= TSEQ; ++t) {
        const unsigned want = (unsigned)(t + 1);
        const ull* hsrc = hbuf + (size_t)(t & 1) * 8192 + (size_t)bg * 1024;

        // Gd prefetch for wave4 finalize (rows q*256+rg*16+u, batch bg*4+bb)
        float gdv[4] = {0.f, 0.f, 0.f, 0.f};
        if (isw4 && t < TSEQ) {
            const float* gb = Gd + ((size_t)t * NB + bg * 4 + ybb) * 1024 + rg * 16 + ycls;
#pragma unroll
            for (int q = 0; q < 4; ++q) gdv[q] = gb[q * 256];
        }
        __builtin_amdgcn_sched_barrier(0);

        // ---- threads 0-255: verify own 4 tagged h-words; convert + stage ----
        if (tid < 256) {
            ull h0, h1, h2, h3;
            for (;;) {
                h0 = __hip_atomic_load(hsrc + tid,       __ATOMIC_RELAXED, __HIP_MEMORY_SCOPE_AGENT);
                h1 = __hip_atomic_load(hsrc + tid + 256, __ATOMIC_RELAXED, __HIP_MEMORY_SCOPE_AGENT);
                h2 = __hip_atomic_load(hsrc + tid + 512, __ATOMIC_RELAXED, __HIP_MEMORY_SCOPE_AGENT);
                h3 = __hip_atomic_load(hsrc + tid + 768, __ATOMIC_RELAXED, __HIP_MEMORY_SCOPE_AGENT);
                if (((unsigned)(h0 >> 32) == want) && ((unsigned)(h1 >> 32) == want) &&
                    ((unsigned)(h2 >> 32) == want) && ((unsigned)(h3 >> 32) == want))
                    break;
                __builtin_amdgcn_s_sleep(1);
            }
            unsigned short hh, hl;
            cvt_split(__uint_as_float((unsigned)h0), hh, hl);
            hbh[0][tid] = hh; hbl[0][tid] = hl;
            cvt_split(__uint_as_float((unsigned)h1), hh, hl);
            hbh[1][tid] = hh; hbl[1][tid] = hl;
            cvt_split(__uint_as_float((unsigned)h2), hh, hl);
            hbh[2][tid] = hh; hbl[2][tid] = hl;
            cvt_split(__uint_as_float((unsigned)h3), hh, hl);
            hbh[3][tid] = hh; hbl[3][tid] = hl;
        }
        __syncthreads();   // hbh/hbl staged

        // ---- MFMA dot: 80 N-rows (64 gates + 16 logits), K=256 ----
        {
            f32x4 acc1 = {}, acc2 = {};
            const int abrow = lane & 3;
            const unsigned short* browh = isw4 ? &lwh[fr][0] : &wbh[wave * 16 + fr][0];
            const unsigned short* browl = isw4 ? &lwl[fr][0] : &wbl[wave * 16 + fr][0];
#pragma unroll
            for (int ks = 0; ks < 8; ++ks) {
                const int kc = ks * 32 + fq * 8;
                bf16x8 ahi = *(const bf16x8*)&hbh[abrow][kc];
                bf16x8 alo = *(const bf16x8*)&hbl[abrow][kc];
                bf16x8 bhi = *(const bf16x8*)&browh[kc];
                bf16x8 blo = *(const bf16x8*)&browl[kc];
                acc1 = __builtin_amdgcn_mfma_f32_16x16x32_bf16(ahi, bhi, acc1, 0, 0, 0);
                acc2 = __builtin_amdgcn_mfma_f32_16x16x32_bf16(ahi, blo, acc2, 0, 0, 0);
                acc2 = __builtin_amdgcn_mfma_f32_16x16x32_bf16(alo, bhi, acc2, 0, 0, 0);
            }
            if (fq == 0) {
#pragma unroll
                for (int reg = 0; reg < 4; ++reg) {
                    float v = acc1[reg] + acc2[reg];
                    if (isw4) lgp[reg][fr] = v;
                    else      gpart[wave][reg][fr] = v;
                }
            }
        }
        __syncthreads();   // gpart + lgp ready

        // ---- wave4 tail: softmax -> y, gates, LSTM, publish ----
        if (isw4) {
            const int bb = ybb, u = ycls;
            // y(t-1) = softmax(logits + lb); y(-1) = 0
            float yv = 0.f;
            if (t > 0) {
                float lv = lgp[bb][u] + lb;
                float m = lv;
#pragma unroll
                for (int o = 1; o < 16; o <<= 1) m = fmaxf(m, __shfl_xor(m, o, 16));
                float e = __expf(lv - m);
                float ss = e;
#pragma unroll
                for (int o = 1; o < 16; o <<= 1) ss += __shfl_xor(ss, o, 16);
                yv = e / ss;
                if (rg == 0)
                    out[(((size_t)(bg * 4 + bb)) * TSEQ + (t - 1)) * NC + u] = yv;
            }
            if (t < TSEQ) {
                float g[4];
#pragma unroll
                for (int q = 0; q < 4; ++q) {
                    float s = gpart[q][bb][u] + gdv[q];
                    const int r = q * 16 + u;
#pragma unroll
                    for (int c = 0; c < 16; ++c) {
                        float yc = __shfl(yv, (lane & 48) | c);
                        s += wylds[r][c] * yc;
                    }
                    g[q] = s;
                }
                float ig = sigf(g[0]), fg = sigf(g[1]);
                float gv = tanhfast(g[2]), og = sigf(g[3]);
                cstate = fg * cstate + ig * gv;
                float h = og * tanhfast(cstate);
                const ull tagbits = ((ull)(unsigned)(t + 2)) << 32;
                const size_t oidx = (size_t)((t + 1) & 1) * 8192
                                  + (size_t)(bg * 4 + bb) * 256 + rg * 16 + u;
                __hip_atomic_store(hbuf + oidx, tagbits | (ull)__float_as_uint(h),
                                   __ATOMIC_RELAXED, __HIP_MEMORY_SCOPE_AGENT);
            }
        }
        if (t == TSEQ) break;
        // no trailing barrier: next-step poll self-gates on wave4's publish,
        // and gpart/hbh rewrites are ordered behind the pre-dot barrier.
    }
}

// ---------------------------------------------------------------------------
extern "C" void kernel_launch(void* const* d_in, const int* in_sizes, int n_in,
                              void* d_out, int out_size, void* d_ws, size_t ws_size,
                              hipStream_t stream)
{
    const float* x     = (const float*)d_in[0];
    const int*   mask  = (const int*)d_in[1];
    const float* Wih_f = (const float*)d_in[2];
    const float* Whh_f = (const float*)d_in[3];
    const float* bih_f = (const float*)d_in[4];
    const float* bhh_f = (const float*)d_in[5];
    const float* Wih_r = (const float*)d_in[6];
    const float* Whh_r = (const float*)d_in[7];
    const float* bih_r = (const float*)d_in[8];
    const float* bhh_r = (const float*)d_in[9];
    const float* fc1_w = (const float*)d_in[10];
    const float* fc2_w = (const float*)d_in[11];
    const float* fc3_w = (const float*)d_in[12];
    const float* fc3_b = (const float*)d_in[13];
    const float* Wih_d = (const float*)d_in[14];
    const float* Whh_d = (const float*)d_in[15];
    const float* bih_d = (const float*)d_in[16];
    const float* bhh_d = (const float*)d_in[17];
    const float* lin_w = (const float*)d_in[18];
    const float* lin_b = (const float*)d_in[19];

    float* ws = (float*)d_ws;
    float* Gf   = ws;
    float* Gr   = ws + 8388608;
    float* hs   = ws + 16777216;
    float* wat  = ws + 25165824;
    float* qp   = ws + 33554432;
    float* kp   = ws + 33718272;
    float* Gd   = ws;
    float* yenc = wat;
    ull* hbuf = (ull*)(wat + 4194304);

    float* outp = (float*)d_out;
    const int M = NB * TSEQ;       // 16384
    dim3 blk(256);

    // 1-2. encoder input projections (split-bf16 MFMA, 128x128 tiles)
    gemm_mfma<1><<<dim3(M / 128, 4), blk, 0, stream>>>(x, DB, Wih_f, DB, bih_f, bhh_f, Gf, 512, DB);
    gemm_mfma<2><<<dim3(M / 128, 4), blk, 0, stream>>>(x, DB, Wih_r, DB, bih_r, bhh_r, Gr, 512, DB);
    // 3. bidirectional recurrence
    enc_scan<<<dim3(64), dim3(512), 0, stream>>>(Gf, Gr, Whh_f, Whh_r, hs);
    // 4-5. q/k projections (tiny N, f32 64x64)
    gemm_nt<0><<<dim3(M / 64, 1), blk, 0, stream>>>(hs, 512, fc1_w, 512, nullptr, nullptr, qp, 10, 10, 256);
    gemm_nt<0><<<dim3(M / 64, 1), blk, 0, stream>>>(hs, 512, fc1_w + 256, 512, nullptr, nullptr, kp, 10, 10, 256);
    // 6. attention scores + softmax
    attn_w<<<dim3(M), blk, 0, stream>>>(qp, kp, mask, fc2_w, wat);
    // 7. ctx = w @ hs (f32 NN)
    bgemm_nn<<<dim3(8, 4, NB), blk, 0, stream>>>(wat, hs);
    // 8. y_enc (split-bf16 MFMA)
    gemm_mfma<0><<<dim3(M / 128, 2), blk, 0, stream>>>(hs, 512, fc3_w, 512, fc3_b, nullptr, yenc, 256, 512);
    // 8.5 decoder comm init
    dec_init5<<<dim3(16), blk, 0, stream>>>(hs, hbuf);
    // 9. decoder input projection (split-bf16 MFMA)
    gemm_mfma<1><<<dim3(M / 128, 8), blk, 0, stream>>>(yenc, 256, Wih_d, 272, bih_d, bhh_d, Gd, 1024, 256);
    // 10. decoder recurrence (single-hop tag sync, fused logit MFMA tile)
    dec_scan10<<<dim3(128), dim3(320), 0, stream>>>(Gd, Whh_d, Wih_d, lin_w, lin_b, hbuf, outp);
}